// Round 1
// baseline (199.322 us; speedup 1.0000x reference)
//
#include <hip/hip_runtime.h>
#include <cstdint>

typedef __bf16 bf16_t;
typedef __bf16 bf16x8 __attribute__((ext_vector_type(8)));
typedef float  f32x4  __attribute__((ext_vector_type(4)));

#define MFMA16(a,b,c) __builtin_amdgcn_mfma_f32_16x16x32_bf16((a),(b),(c),0,0,0)

__device__ __forceinline__ void gload_lds16(const bf16_t* g, bf16_t* l) {
  __builtin_amdgcn_global_load_lds(
      (const __attribute__((address_space(1))) unsigned int*)g,
      (__attribute__((address_space(3))) unsigned int*)l,
      16, 0, 0);
}

// ---------------- convert x (f32) -> bf16 ----------------
__global__ void k_conv_x(const float* __restrict__ x, bf16_t* __restrict__ xb) {
  int i = blockIdx.x * blockDim.x + threadIdx.x;  // 524288 threads, 8 elems each
  const float4* p = reinterpret_cast<const float4*>(x) + (size_t)i * 2;
  float4 a = p[0], b = p[1];
  bf16x8 v;
  v[0]=(bf16_t)a.x; v[1]=(bf16_t)a.y; v[2]=(bf16_t)a.z; v[3]=(bf16_t)a.w;
  v[4]=(bf16_t)b.x; v[5]=(bf16_t)b.y; v[6]=(bf16_t)b.z; v[7]=(bf16_t)b.w;
  *reinterpret_cast<bf16x8*>(xb + (size_t)i * 8) = v;
}

// ---------------- transpose-convert W [K][N] f32 -> WT [N][K] bf16 ----------------
__global__ void k_transpose_w(const float* __restrict__ W, bf16_t* __restrict__ WT,
                              int K, int N) {
  __shared__ float tile[32][33];
  int n0 = blockIdx.x * 32, k0 = blockIdx.y * 32;
  int c = threadIdx.x & 31, r8 = threadIdx.x >> 5;
#pragma unroll
  for (int rr = 0; rr < 4; rr++) {
    int r = r8 + rr * 8;
    tile[r][c] = W[(size_t)(k0 + r) * N + n0 + c];
  }
  __syncthreads();
#pragma unroll
  for (int rr = 0; rr < 4; rr++) {
    int r = r8 + rr * 8;
    WT[(size_t)(n0 + r) * K + k0 + c] = (bf16_t)tile[c][r];
  }
}

// ---------------- transpose V [BH][2048][64] -> VT [BH][64][2048] (bf16) ----------------
__global__ void k_vtrans(const bf16_t* __restrict__ V, bf16_t* __restrict__ VT) {
  __shared__ bf16_t t[64 * 72];
  int bi = blockIdx.x;                   // 32 heads * 32 key-tiles
  int head = bi >> 5, kt = bi & 31;
  int tid = threadIdx.x;
  const bf16_t* src = V + (size_t)head * 131072 + (size_t)kt * 64 * 64;
#pragma unroll
  for (int j = 0; j < 2; j++) {
    int q = tid + 256 * j;
    int key = q >> 3, part = q & 7;
    bf16x8 v = *reinterpret_cast<const bf16x8*>(src + key * 64 + part * 8);
    *reinterpret_cast<bf16x8*>(&t[key * 72 + part * 8]) = v;
  }
  __syncthreads();
  bf16_t* dst = VT + (size_t)head * 131072 + kt * 64;
#pragma unroll
  for (int j = 0; j < 2; j++) {
    int q = tid + 256 * j;
    int dv = q >> 3, part = q & 7;
    bf16x8 v;
#pragma unroll
    for (int e = 0; e < 8; e++) v[e] = t[(part * 8 + e) * 72 + dv];
    *reinterpret_cast<bf16x8*>(dst + (size_t)dv * 2048 + part * 8) = v;
  }
}

// ---------------- GEMM: A[M][K] bf16 @ BT[N][K] bf16 ----------------
// EPI 0: scatter into Q (x0.125), K, V per-head layouts.  EPI 1: f32 out + bias.
template<int EPI>
__global__ __launch_bounds__(256, 2) void k_gemm(
    const bf16_t* __restrict__ A, const bf16_t* __restrict__ BT, int Klen,
    bf16_t* __restrict__ Qo, bf16_t* __restrict__ Ko, bf16_t* __restrict__ Vo,
    const float* __restrict__ bias, float* __restrict__ Out, int Nout) {
  __shared__ bf16_t As[2][4096];
  __shared__ bf16_t Bs[2][4096];
  int tid = threadIdx.x, lane = tid & 63, wid = tid >> 6;
  int row0 = blockIdx.x * 128, col0 = blockIdx.y * 128;
  int wr = wid >> 1, wc = wid & 1;
  int g = lane >> 4, li = lane & 15;

  f32x4 acc[4][4] = {};

  auto stage = [&](int buf, int kt) {
    int k0 = kt * 32;
#pragma unroll
    for (int j = 0; j < 2; j++) {
      int q = tid + 256 * j;
      int r = q >> 2, part = q & 3;
      gload_lds16(A + (size_t)(row0 + r) * Klen + k0 + part * 8,
                  &As[buf][(wid * 64 + j * 256) * 8]);
    }
#pragma unroll
    for (int j = 0; j < 2; j++) {
      int q = tid + 256 * j;
      int r = q >> 2, part = q & 3;
      gload_lds16(BT + (size_t)(col0 + r) * Klen + k0 + part * 8,
                  &Bs[buf][(wid * 64 + j * 256) * 8]);
    }
  };

  int nk = Klen >> 5;
  stage(0, 0);
  for (int kt = 0; kt < nk; kt++) {
    __syncthreads();                       // staging of buf done; prev reads of buf^1 done
    if (kt + 1 < nk) stage((kt + 1) & 1, kt + 1);
    int buf = kt & 1;
    int kl = g * 8;
    bf16x8 a[4], b[4];
#pragma unroll
    for (int m = 0; m < 4; m++)
      a[m] = *reinterpret_cast<const bf16x8*>(&As[buf][(wr * 64 + m * 16 + li) * 32 + kl]);
#pragma unroll
    for (int n = 0; n < 4; n++)
      b[n] = *reinterpret_cast<const bf16x8*>(&Bs[buf][(wc * 64 + n * 16 + li) * 32 + kl]);
#pragma unroll
    for (int m = 0; m < 4; m++)
#pragma unroll
      for (int n = 0; n < 4; n++)
        acc[m][n] = MFMA16(a[m], b[n], acc[m][n]);
  }

#pragma unroll
  for (int m = 0; m < 4; m++) {
    int rg = row0 + wr * 64 + m * 16 + g * 4;
#pragma unroll
    for (int n = 0; n < 4; n++) {
      int cg = col0 + wc * 64 + n * 16 + li;
#pragma unroll
      for (int i = 0; i < 4; i++) {
        float v = acc[m][n][i];
        int row = rg + i;
        if constexpr (EPI == 0) {
          int t = cg >> 10, h = (cg >> 6) & 15, dk = cg & 63;
          int b2 = row >> 11, nn = row & 2047;
          size_t idx = ((size_t)((b2 << 4) + h) * 2048 + nn) * 64 + dk;
          if (t == 0)      Qo[idx] = (bf16_t)(v * 0.125f);
          else if (t == 1) Ko[idx] = (bf16_t)v;
          else             Vo[idx] = (bf16_t)v;
        } else {
          Out[(size_t)row * Nout + cg] = v + bias[cg];
        }
      }
    }
  }
}

// ---------------- flash attention ----------------
// Q [BH][2048][64] (pre-scaled), K [BH][2048][64], VT [BH][64][2048], O bf16 [B,N,H*64]
__global__ __launch_bounds__(256, 2) void k_flash(
    const bf16_t* __restrict__ Q, const bf16_t* __restrict__ K,
    const bf16_t* __restrict__ VT, bf16_t* __restrict__ O) {
  __shared__ bf16_t Qs[128 * 64];
  __shared__ bf16_t Ks[64 * 64];
  __shared__ bf16_t Vs[64 * 64];
  __shared__ bf16_t Ps[4][32 * 64];

  int bi = blockIdx.x;                 // 32 heads * 16 q-tiles
  int head = bi >> 4, qt = bi & 15;
  int tid = threadIdx.x, lane = tid & 63, wid = tid >> 6;
  int g = lane >> 4, li = lane & 15;

  const bf16_t* Qh = Q + (size_t)head * 131072 + (size_t)qt * 128 * 64;
  const bf16_t* Kh = K + (size_t)head * 131072;
  const bf16_t* Vh = VT + (size_t)head * 131072;

  // stage Q once (linear layout)
#pragma unroll
  for (int j = 0; j < 4; j++) {
    int q = tid + 256 * j;
    int r = q >> 3, part = q & 7;
    gload_lds16(Qh + r * 64 + part * 8, &Qs[(wid * 64 + j * 256) * 8]);
  }
  __syncthreads();
  bf16x8 qf[2][2];
#pragma unroll
  for (int mf = 0; mf < 2; mf++)
#pragma unroll
    for (int kd = 0; kd < 2; kd++)
      qf[mf][kd] = *reinterpret_cast<const bf16x8*>(
          &Qs[(wid * 32 + mf * 16 + li) * 64 + kd * 32 + g * 8]);

  f32x4 o[2][4] = {};
  float mrun[2][4], lrun[2][4];
#pragma unroll
  for (int mf = 0; mf < 2; mf++)
#pragma unroll
    for (int i = 0; i < 4; i++) { mrun[mf][i] = -1e30f; lrun[mf][i] = 0.f; }

  char* KsB = (char*)Ks;
  char* VsB = (char*)Vs;
  char* PsB = (char*)&Ps[wid][0];

  for (int t = 0; t < 32; t++) {
    int kv0 = t * 64;
    // stage K tile, source pre-swizzled so swizzled reads land right
#pragma unroll
    for (int j = 0; j < 2; j++) {
      int q = tid + 256 * j;
      int key = q >> 3, part = q & 7;
      gload_lds16(Kh + (size_t)(kv0 + key) * 64 + ((part ^ (key & 7)) * 8),
                  &Ks[(wid * 64 + j * 256) * 8]);
    }
    // stage V^T tile likewise
#pragma unroll
    for (int j = 0; j < 2; j++) {
      int q = tid + 256 * j;
      int dv = q >> 3, part = q & 7;
      gload_lds16(Vh + (size_t)dv * 2048 + kv0 + ((part ^ (dv & 7)) * 8),
                  &Vs[(wid * 64 + j * 256) * 8]);
    }
    __syncthreads();

    // S = Q K^T  (rows: 32 per wave; cols: 64 keys)
    f32x4 s[2][4] = {};
#pragma unroll
    for (int kd = 0; kd < 2; kd++) {
#pragma unroll
      for (int nf = 0; nf < 4; nf++) {
        int key = nf * 16 + li;
        bf16x8 b = *reinterpret_cast<const bf16x8*>(
            KsB + key * 128 + ((kd * 64 + g * 16) ^ ((key & 7) << 4)));
        s[0][nf] = MFMA16(qf[0][kd], b, s[0][nf]);
        s[1][nf] = MFMA16(qf[1][kd], b, s[1][nf]);
      }
    }

    // online softmax (rows owned per-lane: (g,i) within each mf block)
#pragma unroll
    for (int mf = 0; mf < 2; mf++) {
#pragma unroll
      for (int i = 0; i < 4; i++) {
        float v = fmaxf(fmaxf(s[mf][0][i], s[mf][1][i]), fmaxf(s[mf][2][i], s[mf][3][i]));
#pragma unroll
        for (int off = 1; off < 16; off <<= 1) v = fmaxf(v, __shfl_xor(v, off));
        float mnew = fmaxf(mrun[mf][i], v);
        float scale = __expf(mrun[mf][i] - mnew);
        float rs = 0.f;
#pragma unroll
        for (int nf = 0; nf < 4; nf++) {
          float p = __expf(s[mf][nf][i] - mnew);
          s[mf][nf][i] = p;
          rs += p;
        }
#pragma unroll
        for (int off = 1; off < 16; off <<= 1) rs += __shfl_xor(rs, off);
        lrun[mf][i] = lrun[mf][i] * scale + rs;
        mrun[mf][i] = mnew;
#pragma unroll
        for (int nf = 0; nf < 4; nf++) o[mf][nf][i] *= scale;
      }
    }

    // write P (bf16) to per-wave LDS, swizzled
#pragma unroll
    for (int mf = 0; mf < 2; mf++)
#pragma unroll
      for (int nf = 0; nf < 4; nf++)
#pragma unroll
        for (int i = 0; i < 4; i++) {
          int r = mf * 16 + g * 4 + i;
          int c = nf * 16 + li;
          *(bf16_t*)(PsB + r * 128 + ((c * 2) ^ ((r & 7) << 4))) = (bf16_t)s[mf][nf][i];
        }
    __syncthreads();

    // O += P V
#pragma unroll
    for (int kf = 0; kf < 2; kf++) {
      bf16x8 pa[2];
#pragma unroll
      for (int mf = 0; mf < 2; mf++) {
        int r = mf * 16 + li;
        pa[mf] = *reinterpret_cast<const bf16x8*>(
            PsB + r * 128 + ((kf * 64 + g * 16) ^ ((r & 7) << 4)));
      }
#pragma unroll
      for (int nfv = 0; nfv < 4; nfv++) {
        int dv = nfv * 16 + li;
        bf16x8 b = *reinterpret_cast<const bf16x8*>(
            VsB + dv * 128 + ((kf * 64 + g * 16) ^ ((dv & 7) << 4)));
        o[0][nfv] = MFMA16(pa[0], b, o[0][nfv]);
        o[1][nfv] = MFMA16(pa[1], b, o[1][nfv]);
      }
    }
    __syncthreads();
  }

  // epilogue: O /= l, write bf16 into [B, N, H*64]
  int b2 = head >> 4, h = head & 15;
#pragma unroll
  for (int mf = 0; mf < 2; mf++) {
#pragma unroll
    for (int i = 0; i < 4; i++) {
      float inv = 1.f / lrun[mf][i];
      int n = qt * 128 + wid * 32 + mf * 16 + g * 4 + i;
      size_t base = ((size_t)b2 * 2048 + n) * 1024 + h * 64;
#pragma unroll
      for (int nfv = 0; nfv < 4; nfv++)
        O[base + nfv * 16 + li] = (bf16_t)(o[mf][nfv][i] * inv);
    }
  }
}

extern "C" void kernel_launch(void* const* d_in, const int* in_sizes, int n_in,
                              void* d_out, int out_size, void* d_ws, size_t ws_size,
                              hipStream_t stream) {
  const float* x    = (const float*)d_in[0];
  const float* Wqkv = (const float*)d_in[1];
  const float* Wout = (const float*)d_in[2];
  const float* bout = (const float*)d_in[3];
  float* out = (float*)d_out;

  char* ws = (char*)d_ws;
  bf16_t* xb    = (bf16_t*)(ws);                          // 8 MB  [4096][1024]
  bf16_t* wqkvT = (bf16_t*)(ws + ((size_t)8  << 20));     // 6 MB  [3072][1024]
  bf16_t* woutT = (bf16_t*)(ws + ((size_t)14 << 20));     // 2 MB  [1024][1024]
  bf16_t* qw    = (bf16_t*)(ws + ((size_t)16 << 20));     // 8 MB  [32][2048][64]
  bf16_t* kw    = (bf16_t*)(ws + ((size_t)24 << 20));     // 8 MB
  bf16_t* vw    = (bf16_t*)(ws + ((size_t)32 << 20));     // 8 MB
  bf16_t* vtw   = (bf16_t*)(ws + ((size_t)40 << 20));     // 8 MB  [32][64][2048]
  bf16_t* ow    = (bf16_t*)(ws + ((size_t)48 << 20));     // 8 MB  [4096][1024]

  k_conv_x<<<2048, 256, 0, stream>>>(x, xb);
  k_transpose_w<<<dim3(96, 32), 256, 0, stream>>>(Wqkv, wqkvT, 1024, 3072);
  k_transpose_w<<<dim3(32, 32), 256, 0, stream>>>(Wout, woutT, 1024, 1024);
  k_gemm<0><<<dim3(32, 24), 256, 0, stream>>>(xb, wqkvT, 1024, qw, kw, vw,
                                              nullptr, nullptr, 0);
  k_vtrans<<<1024, 256, 0, stream>>>(vw, vtw);
  k_flash<<<512, 256, 0, stream>>>(qw, kw, vtw, ow);
  k_gemm<1><<<dim3(32, 8), 256, 0, stream>>>(ow, woutT, 1024,
                                             nullptr, nullptr, nullptr,
                                             bout, out, 1024);
}

// Round 2
// 175.906 us; speedup vs baseline: 1.1331x; 1.1331x over previous
//
#include <hip/hip_runtime.h>
#include <cstdint>

typedef __bf16 bf16_t;
typedef __bf16 bf16x8 __attribute__((ext_vector_type(8)));
typedef float  f32x4  __attribute__((ext_vector_type(4)));

#define MFMA16(a,b,c) __builtin_amdgcn_mfma_f32_16x16x32_bf16((a),(b),(c),0,0,0)

__device__ __forceinline__ void gload_lds16(const bf16_t* g, bf16_t* l) {
  __builtin_amdgcn_global_load_lds(
      (const __attribute__((address_space(1))) unsigned int*)g,
      (__attribute__((address_space(3))) unsigned int*)l,
      16, 0, 0);
}

// ---------------- convert x (f32) -> bf16 ----------------
__global__ void k_conv_x(const float* __restrict__ x, bf16_t* __restrict__ xb) {
  int i = blockIdx.x * blockDim.x + threadIdx.x;
  const float4* p = reinterpret_cast<const float4*>(x) + (size_t)i * 2;
  float4 a = p[0], b = p[1];
  bf16x8 v;
  v[0]=(bf16_t)a.x; v[1]=(bf16_t)a.y; v[2]=(bf16_t)a.z; v[3]=(bf16_t)a.w;
  v[4]=(bf16_t)b.x; v[5]=(bf16_t)b.y; v[6]=(bf16_t)b.z; v[7]=(bf16_t)b.w;
  *reinterpret_cast<bf16x8*>(xb + (size_t)i * 8) = v;
}

// ---------------- transpose-convert W [K][N] f32 -> WT [N][K] bf16 ----------------
__global__ void k_transpose_w(const float* __restrict__ W, bf16_t* __restrict__ WT,
                              int K, int N) {
  __shared__ float tile[32][33];
  int n0 = blockIdx.x * 32, k0 = blockIdx.y * 32;
  int c = threadIdx.x & 31, r8 = threadIdx.x >> 5;
#pragma unroll
  for (int rr = 0; rr < 4; rr++) {
    int r = r8 + rr * 8;
    tile[r][c] = W[(size_t)(k0 + r) * N + n0 + c];
  }
  __syncthreads();
#pragma unroll
  for (int rr = 0; rr < 4; rr++) {
    int r = r8 + rr * 8;
    WT[(size_t)(n0 + r) * K + k0 + c] = (bf16_t)tile[c][r];
  }
}

// ---------------- transpose V [BH][2048][64] -> VT [BH][64][2048] (bf16) ----------------
__global__ void k_vtrans(const bf16_t* __restrict__ V, bf16_t* __restrict__ VT) {
  __shared__ bf16_t t[64 * 72];
  int bi = blockIdx.x;
  int head = bi >> 5, kt = bi & 31;
  int tid = threadIdx.x;
  const bf16_t* src = V + (size_t)head * 131072 + (size_t)kt * 64 * 64;
#pragma unroll
  for (int j = 0; j < 2; j++) {
    int q = tid + 256 * j;
    int key = q >> 3, part = q & 7;
    bf16x8 v = *reinterpret_cast<const bf16x8*>(src + key * 64 + part * 8);
    *reinterpret_cast<bf16x8*>(&t[key * 72 + part * 8]) = v;
  }
  __syncthreads();
  bf16_t* dst = VT + (size_t)head * 131072 + kt * 64;
#pragma unroll
  for (int j = 0; j < 2; j++) {
    int q = tid + 256 * j;
    int dv = q >> 3, part = q & 7;
    bf16x8 v;
#pragma unroll
    for (int e = 0; e < 8; e++) v[e] = t[(part * 8 + e) * 72 + dv];
    *reinterpret_cast<bf16x8*>(dst + (size_t)dv * 2048 + part * 8) = v;
  }
}

// ---------------- GEMM: A[M][K] bf16 @ BT[N][K] bf16 ----------------
// EPI 0: scatter into Q (x0.125*log2e), K, V per-head layouts.  EPI 1: f32 out + bias.
template<int EPI>
__global__ __launch_bounds__(256, 2) void k_gemm(
    const bf16_t* __restrict__ A, const bf16_t* __restrict__ BT, int Klen,
    bf16_t* __restrict__ Qo, bf16_t* __restrict__ Ko, bf16_t* __restrict__ Vo,
    const float* __restrict__ bias, float* __restrict__ Out, int Nout) {
  __shared__ bf16_t As[2][4096];
  __shared__ bf16_t Bs[2][4096];
  int tid = threadIdx.x, lane = tid & 63, wid = tid >> 6;
  int row0 = blockIdx.x * 128, col0 = blockIdx.y * 128;
  int wr = wid >> 1, wc = wid & 1;
  int g = lane >> 4, li = lane & 15;

  f32x4 acc[4][4] = {};

  auto stage = [&](int buf, int kt) {
    int k0 = kt * 32;
#pragma unroll
    for (int j = 0; j < 2; j++) {
      int q = tid + 256 * j;
      int r = q >> 2, part = q & 3;
      gload_lds16(A + (size_t)(row0 + r) * Klen + k0 + part * 8,
                  &As[buf][(wid * 64 + j * 256) * 8]);
    }
#pragma unroll
    for (int j = 0; j < 2; j++) {
      int q = tid + 256 * j;
      int r = q >> 2, part = q & 3;
      gload_lds16(BT + (size_t)(col0 + r) * Klen + k0 + part * 8,
                  &Bs[buf][(wid * 64 + j * 256) * 8]);
    }
  };

  int nk = Klen >> 5;
  stage(0, 0);
  for (int kt = 0; kt < nk; kt++) {
    __syncthreads();
    if (kt + 1 < nk) stage((kt + 1) & 1, kt + 1);
    int buf = kt & 1;
    int kl = g * 8;
    bf16x8 a[4], b[4];
#pragma unroll
    for (int m = 0; m < 4; m++)
      a[m] = *reinterpret_cast<const bf16x8*>(&As[buf][(wr * 64 + m * 16 + li) * 32 + kl]);
#pragma unroll
    for (int n = 0; n < 4; n++)
      b[n] = *reinterpret_cast<const bf16x8*>(&Bs[buf][(wc * 64 + n * 16 + li) * 32 + kl]);
#pragma unroll
    for (int m = 0; m < 4; m++)
#pragma unroll
      for (int n = 0; n < 4; n++)
        acc[m][n] = MFMA16(a[m], b[n], acc[m][n]);
  }

#pragma unroll
  for (int m = 0; m < 4; m++) {
    int rg = row0 + wr * 64 + m * 16 + g * 4;
#pragma unroll
    for (int n = 0; n < 4; n++) {
      int cg = col0 + wc * 64 + n * 16 + li;
#pragma unroll
      for (int i = 0; i < 4; i++) {
        float v = acc[m][n][i];
        int row = rg + i;
        if constexpr (EPI == 0) {
          int t = cg >> 10, h = (cg >> 6) & 15, dk = cg & 63;
          int b2 = row >> 11, nn = row & 2047;
          size_t idx = ((size_t)((b2 << 4) + h) * 2048 + nn) * 64 + dk;
          // Q pre-scaled by 1/sqrt(d_k) * log2(e) so softmax can use exp2
          if (t == 0)      Qo[idx] = (bf16_t)(v * 0.18033688011112042f);
          else if (t == 1) Ko[idx] = (bf16_t)v;
          else             Vo[idx] = (bf16_t)v;
        } else {
          Out[(size_t)row * Nout + cg] = v + bias[cg];
        }
      }
    }
  }
}

// ---------------- flash attention v2 ----------------
// Q [BH][2048][64] (pre-scaled, log2 units), K [BH][2048][64], VT [BH][64][2048]
// O bf16 [B,N,H*64].  QBLK=64 (1 wave = 16 q-rows), KVBLK=64, K/V double-buffered,
// one barrier per tile, deferred rescale.
__global__ __launch_bounds__(256, 4) void k_flash(
    const bf16_t* __restrict__ Q, const bf16_t* __restrict__ K,
    const bf16_t* __restrict__ VT, bf16_t* __restrict__ O) {
  __shared__ bf16_t Ks[2][64 * 64];
  __shared__ bf16_t Vs[2][64 * 64];
  __shared__ bf16_t Ps[4][16 * 64];

  int bi = blockIdx.x;                 // 32 heads * 32 q-tiles(64 rows)
  int head = bi >> 5, qt = bi & 31;
  int tid = threadIdx.x, lane = tid & 63, wid = tid >> 6;
  int g = lane >> 4, li = lane & 15;

  const bf16_t* Qh = Q + (size_t)head * 131072 + (size_t)qt * 64 * 64;
  const bf16_t* Kh = K + (size_t)head * 131072;
  const bf16_t* Vh = VT + (size_t)head * 131072;

  // Q fragments straight from global (once)
  bf16x8 qf[2];
  {
    const bf16_t* qrow = Qh + (size_t)(wid * 16 + li) * 64;
    qf[0] = *reinterpret_cast<const bf16x8*>(qrow + g * 8);
    qf[1] = *reinterpret_cast<const bf16x8*>(qrow + 32 + g * 8);
  }

  f32x4 o[4] = {};
  float mrun[4], lrun[4];
#pragma unroll
  for (int i = 0; i < 4; i++) { mrun[i] = -1e30f; lrun[i] = 0.f; }

  char* PsB = (char*)&Ps[wid][0];

  auto stage = [&](int buf, int t) {
    int kv0 = t * 64;
#pragma unroll
    for (int j = 0; j < 2; j++) {
      int q = tid + 256 * j;
      int key = q >> 3, part = q & 7;
      gload_lds16(Kh + (size_t)(kv0 + key) * 64 + ((part ^ (key & 7)) * 8),
                  &Ks[buf][(wid * 64 + j * 256) * 8]);
    }
#pragma unroll
    for (int j = 0; j < 2; j++) {
      int q = tid + 256 * j;
      int dv = q >> 3, part = q & 7;
      gload_lds16(Vh + (size_t)dv * 2048 + kv0 + ((part ^ (dv & 7)) * 8),
                  &Vs[buf][(wid * 64 + j * 256) * 8]);
    }
  };

  stage(0, 0);
  for (int t = 0; t < 32; t++) {
    __syncthreads();                 // drains vmcnt: tile t staged; prev reads done
    if (t + 1 < 32) stage((t + 1) & 1, t + 1);   // overlaps with compute below
    int buf = t & 1;
    char* KsB = (char*)&Ks[buf][0];
    char* VsB = (char*)&Vs[buf][0];

    // S = Q K^T   (16 q-rows x 64 keys per wave)
    f32x4 s[4] = {};
#pragma unroll
    for (int kd = 0; kd < 2; kd++)
#pragma unroll
      for (int nf = 0; nf < 4; nf++) {
        int key = nf * 16 + li;
        bf16x8 b = *reinterpret_cast<const bf16x8*>(
            KsB + key * 128 + ((kd * 64 + g * 16) ^ ((key & 7) << 4)));
        s[nf] = MFMA16(qf[kd], b, s[nf]);
      }

    // online softmax (log2 units), deferred rescale (THR = 8)
    float vmax[4];
#pragma unroll
    for (int i = 0; i < 4; i++) {
      float v = fmaxf(fmaxf(s[0][i], s[1][i]), fmaxf(s[2][i], s[3][i]));
#pragma unroll
      for (int off = 1; off < 16; off <<= 1) v = fmaxf(v, __shfl_xor(v, off));
      vmax[i] = v;
    }
    bool ok = true;
#pragma unroll
    for (int i = 0; i < 4; i++) ok &= (vmax[i] <= mrun[i] + 8.f);
    if (!__all(ok)) {
#pragma unroll
      for (int i = 0; i < 4; i++) {
        float mnew = fmaxf(mrun[i], vmax[i]);
        float sc = __builtin_amdgcn_exp2f(mrun[i] - mnew);
        mrun[i] = mnew;
        lrun[i] *= sc;
#pragma unroll
        for (int nf = 0; nf < 4; nf++) o[nf][i] *= sc;
      }
    }
#pragma unroll
    for (int i = 0; i < 4; i++) {
      float rs = 0.f;
#pragma unroll
      for (int nf = 0; nf < 4; nf++) {
        float p = __builtin_amdgcn_exp2f(s[nf][i] - mrun[i]);
        s[nf][i] = p;
        rs += p;
      }
#pragma unroll
      for (int off = 1; off < 16; off <<= 1) rs += __shfl_xor(rs, off);
      lrun[i] += rs;
    }

    // write P (bf16) to per-wave LDS, swizzled; same-wave dep -> no barrier
#pragma unroll
    for (int nf = 0; nf < 4; nf++)
#pragma unroll
      for (int i = 0; i < 4; i++) {
        int r = g * 4 + i;
        int c = nf * 16 + li;
        *(bf16_t*)(PsB + r * 128 + ((c * 2) ^ ((r & 7) << 4))) = (bf16_t)s[nf][i];
      }

    // O += P V
#pragma unroll
    for (int kf = 0; kf < 2; kf++) {
      bf16x8 pa = *reinterpret_cast<const bf16x8*>(
          PsB + li * 128 + ((kf * 64 + g * 16) ^ ((li & 7) << 4)));
#pragma unroll
      for (int nfv = 0; nfv < 4; nfv++) {
        int dv = nfv * 16 + li;
        bf16x8 b = *reinterpret_cast<const bf16x8*>(
            VsB + dv * 128 + ((kf * 64 + g * 16) ^ ((dv & 7) << 4)));
        o[nfv] = MFMA16(pa, b, o[nfv]);
      }
    }
  }

  // epilogue: O /= l, write bf16 into [B, N, H*64]
  int b2 = head >> 4, h = head & 15;
#pragma unroll
  for (int i = 0; i < 4; i++) {
    float inv = 1.f / lrun[i];
    int n = qt * 64 + wid * 16 + g * 4 + i;
    size_t base = ((size_t)b2 * 2048 + n) * 1024 + h * 64;
#pragma unroll
    for (int nfv = 0; nfv < 4; nfv++)
      O[base + nfv * 16 + li] = (bf16_t)(o[nfv][i] * inv);
  }
}

extern "C" void kernel_launch(void* const* d_in, const int* in_sizes, int n_in,
                              void* d_out, int out_size, void* d_ws, size_t ws_size,
                              hipStream_t stream) {
  const float* x    = (const float*)d_in[0];
  const float* Wqkv = (const float*)d_in[1];
  const float* Wout = (const float*)d_in[2];
  const float* bout = (const float*)d_in[3];
  float* out = (float*)d_out;

  char* ws = (char*)d_ws;
  bf16_t* xb    = (bf16_t*)(ws);                          // 8 MB  [4096][1024]
  bf16_t* wqkvT = (bf16_t*)(ws + ((size_t)8  << 20));     // 6 MB  [3072][1024]
  bf16_t* woutT = (bf16_t*)(ws + ((size_t)14 << 20));     // 2 MB  [1024][1024]
  bf16_t* qw    = (bf16_t*)(ws + ((size_t)16 << 20));     // 8 MB  [32][2048][64]
  bf16_t* kw    = (bf16_t*)(ws + ((size_t)24 << 20));     // 8 MB
  bf16_t* vw    = (bf16_t*)(ws + ((size_t)32 << 20));     // 8 MB
  bf16_t* vtw   = (bf16_t*)(ws + ((size_t)40 << 20));     // 8 MB  [32][64][2048]
  bf16_t* ow    = (bf16_t*)(ws + ((size_t)48 << 20));     // 8 MB  [4096][1024]

  k_conv_x<<<2048, 256, 0, stream>>>(x, xb);
  k_transpose_w<<<dim3(96, 32), 256, 0, stream>>>(Wqkv, wqkvT, 1024, 3072);
  k_transpose_w<<<dim3(32, 32), 256, 0, stream>>>(Wout, woutT, 1024, 1024);
  k_gemm<0><<<dim3(32, 24), 256, 0, stream>>>(xb, wqkvT, 1024, qw, kw, vw,
                                              nullptr, nullptr, 0);
  k_vtrans<<<1024, 256, 0, stream>>>(vw, vtw);
  k_flash<<<1024, 256, 0, stream>>>(qw, kw, vtw, ow);
  k_gemm<1><<<dim3(32, 8), 256, 0, stream>>>(ow, woutT, 1024,
                                             nullptr, nullptr, nullptr,
                                             bout, out, 1024);
}

// Round 3
// 141.296 us; speedup vs baseline: 1.4107x; 1.2450x over previous
//
#include <hip/hip_runtime.h>
#include <cstdint>

typedef __bf16 bf16_t;
typedef __bf16 bf16x8 __attribute__((ext_vector_type(8)));
typedef float  f32x4  __attribute__((ext_vector_type(4)));

#define MFMA16(a,b,c) __builtin_amdgcn_mfma_f32_16x16x32_bf16((a),(b),(c),0,0,0)

__device__ __forceinline__ void gload_lds16(const bf16_t* g, bf16_t* l) {
  __builtin_amdgcn_global_load_lds(
      (const __attribute__((address_space(1))) unsigned int*)g,
      (__attribute__((address_space(3))) unsigned int*)l,
      16, 0, 0);
}

// ---------------- convert x (f32) -> bf16 ----------------
__global__ void k_conv_x(const float* __restrict__ x, bf16_t* __restrict__ xb) {
  int i = blockIdx.x * blockDim.x + threadIdx.x;
  const float4* p = reinterpret_cast<const float4*>(x) + (size_t)i * 2;
  float4 a = p[0], b = p[1];
  bf16x8 v;
  v[0]=(bf16_t)a.x; v[1]=(bf16_t)a.y; v[2]=(bf16_t)a.z; v[3]=(bf16_t)a.w;
  v[4]=(bf16_t)b.x; v[5]=(bf16_t)b.y; v[6]=(bf16_t)b.z; v[7]=(bf16_t)b.w;
  *reinterpret_cast<bf16x8*>(xb + (size_t)i * 8) = v;
}

// ---------------- transpose-convert W [K][N] f32 -> WT [N][K] bf16 ----------------
__global__ void k_transpose_w(const float* __restrict__ W, bf16_t* __restrict__ WT,
                              int K, int N) {
  __shared__ float tile[32][33];
  int n0 = blockIdx.x * 32, k0 = blockIdx.y * 32;
  int c = threadIdx.x & 31, r8 = threadIdx.x >> 5;
#pragma unroll
  for (int rr = 0; rr < 4; rr++) {
    int r = r8 + rr * 8;
    tile[r][c] = W[(size_t)(k0 + r) * N + n0 + c];
  }
  __syncthreads();
#pragma unroll
  for (int rr = 0; rr < 4; rr++) {
    int r = r8 + rr * 8;
    WT[(size_t)(n0 + r) * K + k0 + c] = (bf16_t)tile[c][r];
  }
}

// ---------------- transpose V [BH][2048][64] -> VT [BH][64][2048] (bf16) ----------------
__global__ void k_vtrans(const bf16_t* __restrict__ V, bf16_t* __restrict__ VT) {
  __shared__ bf16_t t[64 * 72];
  int bi = blockIdx.x;
  int head = bi >> 5, kt = bi & 31;
  int tid = threadIdx.x;
  const bf16_t* src = V + (size_t)head * 131072 + (size_t)kt * 64 * 64;
#pragma unroll
  for (int j = 0; j < 2; j++) {
    int q = tid + 256 * j;
    int key = q >> 3, part = q & 7;
    bf16x8 v = *reinterpret_cast<const bf16x8*>(src + key * 64 + part * 8);
    *reinterpret_cast<bf16x8*>(&t[key * 72 + part * 8]) = v;
  }
  __syncthreads();
  bf16_t* dst = VT + (size_t)head * 131072 + kt * 64;
#pragma unroll
  for (int j = 0; j < 2; j++) {
    int q = tid + 256 * j;
    int dv = q >> 3, part = q & 7;
    bf16x8 v;
#pragma unroll
    for (int e = 0; e < 8; e++) v[e] = t[(part * 8 + e) * 72 + dv];
    *reinterpret_cast<bf16x8*>(dst + (size_t)dv * 2048 + part * 8) = v;
  }
}

// ---------------- GEMM: A[M][K] bf16 @ BT[N][K] bf16 ----------------
// EPI 0: scatter into Q (x0.125*log2e), K, V per-head layouts.  EPI 1: f32 out + bias.
template<int EPI>
__global__ __launch_bounds__(256, 2) void k_gemm(
    const bf16_t* __restrict__ A, const bf16_t* __restrict__ BT, int Klen,
    bf16_t* __restrict__ Qo, bf16_t* __restrict__ Ko, bf16_t* __restrict__ Vo,
    const float* __restrict__ bias, float* __restrict__ Out, int Nout) {
  __shared__ bf16_t As[2][4096];
  __shared__ bf16_t Bs[2][4096];
  int tid = threadIdx.x, lane = tid & 63, wid = tid >> 6;
  int row0 = blockIdx.x * 128, col0 = blockIdx.y * 128;
  int wr = wid >> 1, wc = wid & 1;
  int g = lane >> 4, li = lane & 15;

  f32x4 acc[4][4] = {};

  auto stage = [&](int buf, int kt) {
    int k0 = kt * 32;
#pragma unroll
    for (int j = 0; j < 2; j++) {
      int q = tid + 256 * j;
      int r = q >> 2, part = q & 3;
      gload_lds16(A + (size_t)(row0 + r) * Klen + k0 + part * 8,
                  &As[buf][(wid * 64 + j * 256) * 8]);
    }
#pragma unroll
    for (int j = 0; j < 2; j++) {
      int q = tid + 256 * j;
      int r = q >> 2, part = q & 3;
      gload_lds16(BT + (size_t)(col0 + r) * Klen + k0 + part * 8,
                  &Bs[buf][(wid * 64 + j * 256) * 8]);
    }
  };

  int nk = Klen >> 5;
  stage(0, 0);
  for (int kt = 0; kt < nk; kt++) {
    __syncthreads();
    if (kt + 1 < nk) stage((kt + 1) & 1, kt + 1);
    int buf = kt & 1;
    int kl = g * 8;
    bf16x8 a[4], b[4];
#pragma unroll
    for (int m = 0; m < 4; m++)
      a[m] = *reinterpret_cast<const bf16x8*>(&As[buf][(wr * 64 + m * 16 + li) * 32 + kl]);
#pragma unroll
    for (int n = 0; n < 4; n++)
      b[n] = *reinterpret_cast<const bf16x8*>(&Bs[buf][(wc * 64 + n * 16 + li) * 32 + kl]);
#pragma unroll
    for (int m = 0; m < 4; m++)
#pragma unroll
      for (int n = 0; n < 4; n++)
        acc[m][n] = MFMA16(a[m], b[n], acc[m][n]);
  }

#pragma unroll
  for (int m = 0; m < 4; m++) {
    int rg = row0 + wr * 64 + m * 16 + g * 4;
#pragma unroll
    for (int n = 0; n < 4; n++) {
      int cg = col0 + wc * 64 + n * 16 + li;
#pragma unroll
      for (int i = 0; i < 4; i++) {
        float v = acc[m][n][i];
        int row = rg + i;
        if constexpr (EPI == 0) {
          int t = cg >> 10, h = (cg >> 6) & 15, dk = cg & 63;
          int b2 = row >> 11, nn = row & 2047;
          size_t idx = ((size_t)((b2 << 4) + h) * 2048 + nn) * 64 + dk;
          // Q pre-scaled by 1/sqrt(d_k) * log2(e) so softmax can use exp2
          if (t == 0)      Qo[idx] = (bf16_t)(v * 0.18033688011112042f);
          else if (t == 1) Ko[idx] = (bf16_t)v;
          else             Vo[idx] = (bf16_t)v;
        } else {
          Out[(size_t)row * Nout + cg] = v + bias[cg];
        }
      }
    }
  }
}

// ---------------- flash attention v3 ----------------
// Q [BH][2048][64] (pre-scaled, log2 units), K [BH][2048][64], VT [BH][64][2048]
// O bf16 [B,N,H*64].  QBLK=64 (1 wave = 16 q-rows), KVBLK=64, double-buffered,
// one barrier per tile.  v3: vote-gated deferred max (no per-tile max reduce),
// end-deferred sum (no per-tile sum reduce), XCD-aware block swizzle.
__global__ __launch_bounds__(256, 4) void k_flash(
    const bf16_t* __restrict__ Q, const bf16_t* __restrict__ K,
    const bf16_t* __restrict__ VT, bf16_t* __restrict__ O) {
  __shared__ bf16_t Ks[2][64 * 64];
  __shared__ bf16_t Vs[2][64 * 64];
  __shared__ bf16_t Ps[4][16 * 64];

  // XCD swizzle: grid 1024 = 8 XCDs x 128; XCD x serves heads 4x..4x+3
  int bi = (blockIdx.x & 7) * 128 + (blockIdx.x >> 3);
  int head = bi >> 5, qt = bi & 31;
  int tid = threadIdx.x, lane = tid & 63, wid = tid >> 6;
  int g = lane >> 4, li = lane & 15;

  const bf16_t* Qh = Q + (size_t)head * 131072 + (size_t)qt * 64 * 64;
  const bf16_t* Kh = K + (size_t)head * 131072;
  const bf16_t* Vh = VT + (size_t)head * 131072;

  // Q fragments straight from global (once)
  bf16x8 qf[2];
  {
    const bf16_t* qrow = Qh + (size_t)(wid * 16 + li) * 64;
    qf[0] = *reinterpret_cast<const bf16x8*>(qrow + g * 8);
    qf[1] = *reinterpret_cast<const bf16x8*>(qrow + 32 + g * 8);
  }

  f32x4 o[4] = {};
  float mrun[4], lrun[4];
#pragma unroll
  for (int i = 0; i < 4; i++) { mrun[i] = -1e30f; lrun[i] = 0.f; }

  char* PsB = (char*)&Ps[wid][0];

  auto stage = [&](int buf, int t) {
    int kv0 = t * 64;
#pragma unroll
    for (int j = 0; j < 2; j++) {
      int q = tid + 256 * j;
      int key = q >> 3, part = q & 7;
      gload_lds16(Kh + (size_t)(kv0 + key) * 64 + ((part ^ (key & 7)) * 8),
                  &Ks[buf][(wid * 64 + j * 256) * 8]);
    }
#pragma unroll
    for (int j = 0; j < 2; j++) {
      int q = tid + 256 * j;
      int dv = q >> 3, part = q & 7;
      gload_lds16(Vh + (size_t)dv * 2048 + kv0 + ((part ^ (dv & 7)) * 8),
                  &Vs[buf][(wid * 64 + j * 256) * 8]);
    }
  };

  stage(0, 0);
  for (int t = 0; t < 32; t++) {
    __syncthreads();                 // drains vmcnt: tile t staged; prev reads done
    if (t + 1 < 32) stage((t + 1) & 1, t + 1);   // overlaps with compute below
    int buf = t & 1;
    char* KsB = (char*)&Ks[buf][0];
    char* VsB = (char*)&Vs[buf][0];

    // S = Q K^T   (16 q-rows x 64 keys per wave)
    f32x4 s[4] = {};
#pragma unroll
    for (int kd = 0; kd < 2; kd++)
#pragma unroll
      for (int nf = 0; nf < 4; nf++) {
        int key = nf * 16 + li;
        bf16x8 b = *reinterpret_cast<const bf16x8*>(
            KsB + key * 128 + ((kd * 64 + g * 16) ^ ((key & 7) << 4)));
        s[nf] = MFMA16(qf[kd], b, s[nf]);
      }

    // ---- softmax (log2 units), vote-gated deferred max ----
    // per-lane partial max over this lane's 4 columns of each row
    float pmax[4];
#pragma unroll
    for (int i = 0; i < 4; i++)
      pmax[i] = fmaxf(fmaxf(s[0][i], s[1][i]), fmaxf(s[2][i], s[3][i]));
    bool ok = true;
#pragma unroll
    for (int i = 0; i < 4; i++) ok &= (pmax[i] <= mrun[i] + 8.f);
    if (!__all(ok)) {
      // rare: true row max via 16-lane butterfly, rescale o and lrun
#pragma unroll
      for (int i = 0; i < 4; i++) {
        float v = pmax[i];
#pragma unroll
        for (int off = 1; off < 16; off <<= 1) v = fmaxf(v, __shfl_xor(v, off));
        float mnew = fmaxf(mrun[i], v);
        float sc = __builtin_amdgcn_exp2f(mrun[i] - mnew);
        mrun[i] = mnew;
        lrun[i] *= sc;
#pragma unroll
        for (int nf = 0; nf < 4; nf++) o[nf][i] *= sc;
      }
    }
    // P = exp2(s - mrun), lane-partial sum accumulate (reduced once at end)
#pragma unroll
    for (int i = 0; i < 4; i++) {
      float rs = 0.f;
#pragma unroll
      for (int nf = 0; nf < 4; nf++) {
        float p = __builtin_amdgcn_exp2f(s[nf][i] - mrun[i]);
        s[nf][i] = p;
        rs += p;
      }
      lrun[i] += rs;
    }

    // write P (bf16) to per-wave LDS, swizzled; same-wave dep -> no barrier
#pragma unroll
    for (int nf = 0; nf < 4; nf++)
#pragma unroll
      for (int i = 0; i < 4; i++) {
        int r = g * 4 + i;
        int c = nf * 16 + li;
        *(bf16_t*)(PsB + r * 128 + ((c * 2) ^ ((r & 7) << 4))) = (bf16_t)s[nf][i];
      }

    // O += P V
#pragma unroll
    for (int kf = 0; kf < 2; kf++) {
      bf16x8 pa = *reinterpret_cast<const bf16x8*>(
          PsB + li * 128 + ((kf * 64 + g * 16) ^ ((li & 7) << 4)));
#pragma unroll
      for (int nfv = 0; nfv < 4; nfv++) {
        int dv = nfv * 16 + li;
        bf16x8 b = *reinterpret_cast<const bf16x8*>(
            VsB + dv * 128 + ((kf * 64 + g * 16) ^ ((dv & 7) << 4)));
        o[nfv] = MFMA16(pa, b, o[nfv]);
      }
    }
  }

  // epilogue: reduce lane-partial lrun across the 16 lanes of each row,
  // then O /= l, write bf16 into [B, N, H*64]
#pragma unroll
  for (int i = 0; i < 4; i++) {
#pragma unroll
    for (int off = 1; off < 16; off <<= 1) lrun[i] += __shfl_xor(lrun[i], off);
  }
  int b2 = head >> 4, h = head & 15;
#pragma unroll
  for (int i = 0; i < 4; i++) {
    float inv = 1.f / lrun[i];
    int n = qt * 64 + wid * 16 + g * 4 + i;
    size_t base = ((size_t)b2 * 2048 + n) * 1024 + h * 64;
#pragma unroll
    for (int nfv = 0; nfv < 4; nfv++)
      O[base + nfv * 16 + li] = (bf16_t)(o[nfv][i] * inv);
  }
}

extern "C" void kernel_launch(void* const* d_in, const int* in_sizes, int n_in,
                              void* d_out, int out_size, void* d_ws, size_t ws_size,
                              hipStream_t stream) {
  const float* x    = (const float*)d_in[0];
  const float* Wqkv = (const float*)d_in[1];
  const float* Wout = (const float*)d_in[2];
  const float* bout = (const float*)d_in[3];
  float* out = (float*)d_out;

  char* ws = (char*)d_ws;
  bf16_t* xb    = (bf16_t*)(ws);                          // 8 MB  [4096][1024]
  bf16_t* wqkvT = (bf16_t*)(ws + ((size_t)8  << 20));     // 6 MB  [3072][1024]
  bf16_t* woutT = (bf16_t*)(ws + ((size_t)14 << 20));     // 2 MB  [1024][1024]
  bf16_t* qw    = (bf16_t*)(ws + ((size_t)16 << 20));     // 8 MB  [32][2048][64]
  bf16_t* kw    = (bf16_t*)(ws + ((size_t)24 << 20));     // 8 MB
  bf16_t* vw    = (bf16_t*)(ws + ((size_t)32 << 20));     // 8 MB
  bf16_t* vtw   = (bf16_t*)(ws + ((size_t)40 << 20));     // 8 MB  [32][64][2048]
  bf16_t* ow    = (bf16_t*)(ws + ((size_t)48 << 20));     // 8 MB  [4096][1024]

  k_conv_x<<<2048, 256, 0, stream>>>(x, xb);
  k_transpose_w<<<dim3(96, 32), 256, 0, stream>>>(Wqkv, wqkvT, 1024, 3072);
  k_transpose_w<<<dim3(32, 32), 256, 0, stream>>>(Wout, woutT, 1024, 1024);
  k_gemm<0><<<dim3(32, 24), 256, 0, stream>>>(xb, wqkvT, 1024, qw, kw, vw,
                                              nullptr, nullptr, 0);
  k_vtrans<<<1024, 256, 0, stream>>>(vw, vtw);
  k_flash<<<1024, 256, 0, stream>>>(qw, kw, vtw, ow);
  k_gemm<1><<<dim3(32, 8), 256, 0, stream>>>(ow, woutT, 1024,
                                             nullptr, nullptr, nullptr,
                                             bout, out, 1024);
}

// Round 4
// 129.054 us; speedup vs baseline: 1.5445x; 1.0949x over previous
//
#include <hip/hip_runtime.h>
#include <cstdint>

typedef __bf16 bf16_t;
typedef __bf16 bf16x8 __attribute__((ext_vector_type(8)));
typedef float  f32x4  __attribute__((ext_vector_type(4)));
typedef uint32_t u32x4 __attribute__((ext_vector_type(4)));

#define MFMA16(a,b,c) __builtin_amdgcn_mfma_f32_16x16x32_bf16((a),(b),(c),0,0,0)

__device__ __forceinline__ void gload_lds16(const bf16_t* g, bf16_t* l) {
  __builtin_amdgcn_global_load_lds(
      (const __attribute__((address_space(1))) unsigned int*)g,
      (__attribute__((address_space(3))) unsigned int*)l,
      16, 0, 0);
}

__device__ __forceinline__ uint32_t cvt_pk_bf16(float lo, float hi) {
  uint32_t r;
  asm("v_cvt_pk_bf16_f32 %0, %1, %2" : "=v"(r) : "v"(lo), "v"(hi));
  return r;
}

// ---------------- convert x (f32) -> bf16 ----------------
__global__ void k_conv_x(const float* __restrict__ x, bf16_t* __restrict__ xb) {
  int i = blockIdx.x * blockDim.x + threadIdx.x;
  const float4* p = reinterpret_cast<const float4*>(x) + (size_t)i * 2;
  float4 a = p[0], b = p[1];
  bf16x8 v;
  v[0]=(bf16_t)a.x; v[1]=(bf16_t)a.y; v[2]=(bf16_t)a.z; v[3]=(bf16_t)a.w;
  v[4]=(bf16_t)b.x; v[5]=(bf16_t)b.y; v[6]=(bf16_t)b.z; v[7]=(bf16_t)b.w;
  *reinterpret_cast<bf16x8*>(xb + (size_t)i * 8) = v;
}

// ---------------- transpose-convert W [K][N] f32 -> WT [N][K] bf16 ----------------
__global__ void k_transpose_w(const float* __restrict__ W, bf16_t* __restrict__ WT,
                              int K, int N) {
  __shared__ float tile[32][33];
  int n0 = blockIdx.x * 32, k0 = blockIdx.y * 32;
  int c = threadIdx.x & 31, r8 = threadIdx.x >> 5;
#pragma unroll
  for (int rr = 0; rr < 4; rr++) {
    int r = r8 + rr * 8;
    tile[r][c] = W[(size_t)(k0 + r) * N + n0 + c];
  }
  __syncthreads();
#pragma unroll
  for (int rr = 0; rr < 4; rr++) {
    int r = r8 + rr * 8;
    WT[(size_t)(n0 + r) * K + k0 + c] = (bf16_t)tile[c][r];
  }
}

// ---------------- transpose V [BH][2048][64] -> VT [BH][64][2048] (bf16) ----------------
__global__ void k_vtrans(const bf16_t* __restrict__ V, bf16_t* __restrict__ VT) {
  __shared__ bf16_t t[64 * 72];
  int bi = blockIdx.x;
  int head = bi >> 5, kt = bi & 31;
  int tid = threadIdx.x;
  const bf16_t* src = V + (size_t)head * 131072 + (size_t)kt * 64 * 64;
#pragma unroll
  for (int j = 0; j < 2; j++) {
    int q = tid + 256 * j;
    int key = q >> 3, part = q & 7;
    bf16x8 v = *reinterpret_cast<const bf16x8*>(src + key * 64 + part * 8);
    *reinterpret_cast<bf16x8*>(&t[key * 72 + part * 8]) = v;
  }
  __syncthreads();
  bf16_t* dst = VT + (size_t)head * 131072 + kt * 64;
#pragma unroll
  for (int j = 0; j < 2; j++) {
    int q = tid + 256 * j;
    int dv = q >> 3, part = q & 7;
    bf16x8 v;
#pragma unroll
    for (int e = 0; e < 8; e++) v[e] = t[(part * 8 + e) * 72 + dv];
    *reinterpret_cast<bf16x8*>(dst + (size_t)dv * 2048 + part * 8) = v;
  }
}

// ---------------- GEMM: A[M][K] bf16 @ BT[N][K] bf16 ----------------
template<int EPI>
__global__ __launch_bounds__(256, 2) void k_gemm(
    const bf16_t* __restrict__ A, const bf16_t* __restrict__ BT, int Klen,
    bf16_t* __restrict__ Qo, bf16_t* __restrict__ Ko, bf16_t* __restrict__ Vo,
    const float* __restrict__ bias, float* __restrict__ Out, int Nout) {
  __shared__ bf16_t As[2][4096];
  __shared__ bf16_t Bs[2][4096];
  int tid = threadIdx.x, lane = tid & 63, wid = tid >> 6;
  int row0 = blockIdx.x * 128, col0 = blockIdx.y * 128;
  int wr = wid >> 1, wc = wid & 1;
  int g = lane >> 4, li = lane & 15;

  f32x4 acc[4][4] = {};

  auto stage = [&](int buf, int kt) {
    int k0 = kt * 32;
#pragma unroll
    for (int j = 0; j < 2; j++) {
      int q = tid + 256 * j;
      int r = q >> 2, part = q & 3;
      gload_lds16(A + (size_t)(row0 + r) * Klen + k0 + part * 8,
                  &As[buf][(wid * 64 + j * 256) * 8]);
    }
#pragma unroll
    for (int j = 0; j < 2; j++) {
      int q = tid + 256 * j;
      int r = q >> 2, part = q & 3;
      gload_lds16(BT + (size_t)(col0 + r) * Klen + k0 + part * 8,
                  &Bs[buf][(wid * 64 + j * 256) * 8]);
    }
  };

  int nk = Klen >> 5;
  stage(0, 0);
  for (int kt = 0; kt < nk; kt++) {
    __syncthreads();
    if (kt + 1 < nk) stage((kt + 1) & 1, kt + 1);
    int buf = kt & 1;
    int kl = g * 8;
    bf16x8 a[4], b[4];
#pragma unroll
    for (int m = 0; m < 4; m++)
      a[m] = *reinterpret_cast<const bf16x8*>(&As[buf][(wr * 64 + m * 16 + li) * 32 + kl]);
#pragma unroll
    for (int n = 0; n < 4; n++)
      b[n] = *reinterpret_cast<const bf16x8*>(&Bs[buf][(wc * 64 + n * 16 + li) * 32 + kl]);
#pragma unroll
    for (int m = 0; m < 4; m++)
#pragma unroll
      for (int n = 0; n < 4; n++)
        acc[m][n] = MFMA16(a[m], b[n], acc[m][n]);
  }

#pragma unroll
  for (int m = 0; m < 4; m++) {
    int rg = row0 + wr * 64 + m * 16 + g * 4;
#pragma unroll
    for (int n = 0; n < 4; n++) {
      int cg = col0 + wc * 64 + n * 16 + li;
#pragma unroll
      for (int i = 0; i < 4; i++) {
        float v = acc[m][n][i];
        int row = rg + i;
        if constexpr (EPI == 0) {
          int t = cg >> 10, h = (cg >> 6) & 15, dk = cg & 63;
          int b2 = row >> 11, nn = row & 2047;
          size_t idx = ((size_t)((b2 << 4) + h) * 2048 + nn) * 64 + dk;
          // Q pre-scaled by 1/sqrt(d_k) * log2(e) so softmax can use exp2
          if (t == 0)      Qo[idx] = (bf16_t)(v * 0.18033688011112042f);
          else if (t == 1) Ko[idx] = (bf16_t)v;
          else             Vo[idx] = (bf16_t)v;
        } else {
          Out[(size_t)row * Nout + cg] = v + bias[cg];
        }
      }
    }
  }
}

// ---------------- flash attention v4 ----------------
// Swapped QK^T (S^T = K·Q^T) with permuted key assignment so P is fully
// lane-local for PV's A-operand: zero LDS P bounce, zero cross-lane exchange.
// key_of(nf, r) = (r>>2)*8 + (nf&1)*4 + (r&3) + (nf>>1)*32
// Lane (g,li): owns q-row li, keys g*8 + (nf&1)*4 + i + (nf>>1)*32.
// Ks swizzle uses key bits 0..4: SW(key) = (key&7) ^ (((key>>3)&3)<<1).
__global__ __launch_bounds__(256, 4) void k_flash(
    const bf16_t* __restrict__ Q, const bf16_t* __restrict__ K,
    const bf16_t* __restrict__ VT, bf16_t* __restrict__ O) {
  __shared__ bf16_t Ks[2][64 * 64];
  __shared__ bf16_t Vs[2][64 * 64];

  // XCD swizzle: grid 1024 = 8 XCDs x 128; XCD x serves heads 4x..4x+3
  int bi = (blockIdx.x & 7) * 128 + (blockIdx.x >> 3);
  int head = bi >> 5, qt = bi & 31;
  int tid = threadIdx.x, lane = tid & 63, wid = tid >> 6;
  int g = lane >> 4, li = lane & 15;

  const bf16_t* Qh = Q + (size_t)head * 131072 + (size_t)qt * 64 * 64;
  const bf16_t* Kh = K + (size_t)head * 131072;
  const bf16_t* Vh = VT + (size_t)head * 131072;

  // Q B-fragments (col = qrow = li, k = dims g*8..), straight from global
  bf16x8 qf[2];
  {
    const bf16_t* qrow = Qh + (size_t)(wid * 16 + li) * 64;
    qf[0] = *reinterpret_cast<const bf16x8*>(qrow + g * 8);
    qf[1] = *reinterpret_cast<const bf16x8*>(qrow + 32 + g * 8);
  }

  f32x4 o[4] = {};
  float mrun = -1e30f, lrun = 0.f;   // softmax state for q-row li (per lane)

  auto stage = [&](int buf, int t) {
    int kv0 = t * 64;
#pragma unroll
    for (int j = 0; j < 2; j++) {
      int q = tid + 256 * j;
      int key = q >> 3, part = q & 7;
      int sw = (key & 7) ^ (((key >> 3) & 3) << 1);
      gload_lds16(Kh + (size_t)(kv0 + key) * 64 + ((part ^ sw) * 8),
                  &Ks[buf][(wid * 64 + j * 256) * 8]);
    }
#pragma unroll
    for (int j = 0; j < 2; j++) {
      int q = tid + 256 * j;
      int dv = q >> 3, part = q & 7;
      gload_lds16(Vh + (size_t)dv * 2048 + kv0 + ((part ^ (dv & 7)) * 8),
                  &Vs[buf][(wid * 64 + j * 256) * 8]);
    }
  };

  stage(0, 0);
  for (int t = 0; t < 32; t++) {
    __syncthreads();                 // tile t staged; prev reads of buf done
    if (t + 1 < 32) stage((t + 1) & 1, t + 1);   // overlaps with compute below
    int buf = t & 1;
    char* KsB = (char*)&Ks[buf][0];
    char* VsB = (char*)&Vs[buf][0];

    // S^T = K · Q^T : fragment nf rows hold keys key_of(nf, r)
    f32x4 s[4] = {};
    __builtin_amdgcn_s_setprio(1);
#pragma unroll
    for (int kd = 0; kd < 2; kd++)
#pragma unroll
      for (int nf = 0; nf < 4; nf++) {
        int key = ((li >> 2) << 3) | ((nf & 1) << 2) | (li & 3) | ((nf >> 1) << 5);
        int sw = (key & 7) ^ (((key >> 3) & 3) << 1);
        bf16x8 a = *reinterpret_cast<const bf16x8*>(
            KsB + key * 128 + (((kd * 4 + g) ^ sw) << 4));
        s[nf] = MFMA16(a, qf[kd], s[nf]);
      }
    __builtin_amdgcn_s_setprio(0);

    // ---- softmax (log2 units), row = li, 16 lane-local scores ----
    float m0 = fmaxf(fmaxf(s[0][0], s[0][1]), fmaxf(s[0][2], s[0][3]));
    float m1 = fmaxf(fmaxf(s[1][0], s[1][1]), fmaxf(s[1][2], s[1][3]));
    float m2 = fmaxf(fmaxf(s[2][0], s[2][1]), fmaxf(s[2][2], s[2][3]));
    float m3 = fmaxf(fmaxf(s[3][0], s[3][1]), fmaxf(s[3][2], s[3][3]));
    float pmax = fmaxf(fmaxf(m0, m1), fmaxf(m2, m3));
    if (!__all(pmax <= mrun + 8.f)) {
      // rare: true row max across the 4 g-group lanes, rescale o and lrun
      float v = pmax;
      v = fmaxf(v, __shfl_xor(v, 16));
      v = fmaxf(v, __shfl_xor(v, 32));
      float mnew = fmaxf(mrun, v);
      float sc = __builtin_amdgcn_exp2f(mrun - mnew);
      mrun = mnew;
      lrun *= sc;
      float osc[4];
#pragma unroll
      for (int i = 0; i < 4; i++) osc[i] = __shfl(sc, g * 4 + i);
#pragma unroll
      for (int nf = 0; nf < 4; nf++)
#pragma unroll
        for (int i = 0; i < 4; i++) o[nf][i] *= osc[i];
    }
    float rs = 0.f;
#pragma unroll
    for (int nf = 0; nf < 4; nf++)
#pragma unroll
      for (int i = 0; i < 4; i++) {
        float p = __builtin_amdgcn_exp2f(s[nf][i] - mrun);
        s[nf][i] = p;
        rs += p;
      }
    lrun += rs;

    // pack P into PV A-fragments: fully lane-local (key_of ownership)
    u32x4 w0, w1;
    w0[0] = cvt_pk_bf16(s[0][0], s[0][1]);
    w0[1] = cvt_pk_bf16(s[0][2], s[0][3]);
    w0[2] = cvt_pk_bf16(s[1][0], s[1][1]);
    w0[3] = cvt_pk_bf16(s[1][2], s[1][3]);
    w1[0] = cvt_pk_bf16(s[2][0], s[2][1]);
    w1[1] = cvt_pk_bf16(s[2][2], s[2][3]);
    w1[2] = cvt_pk_bf16(s[3][0], s[3][1]);
    w1[3] = cvt_pk_bf16(s[3][2], s[3][3]);
    bf16x8 pa0 = __builtin_bit_cast(bf16x8, w0);
    bf16x8 pa1 = __builtin_bit_cast(bf16x8, w1);

    // O += P V   (A = P from registers, B = V^T from LDS)
    __builtin_amdgcn_s_setprio(1);
#pragma unroll
    for (int nfv = 0; nfv < 4; nfv++) {
      int dv = nfv * 16 + li;
      bf16x8 b0 = *reinterpret_cast<const bf16x8*>(
          VsB + dv * 128 + ((g * 16) ^ ((dv & 7) << 4)));
      o[nfv] = MFMA16(pa0, b0, o[nfv]);
      bf16x8 b1 = *reinterpret_cast<const bf16x8*>(
          VsB + dv * 128 + ((64 + g * 16) ^ ((dv & 7) << 4)));
      o[nfv] = MFMA16(pa1, b1, o[nfv]);
    }
    __builtin_amdgcn_s_setprio(0);
  }

  // epilogue: full row-sums (4 lanes per row), redistribute 1/l, write O
  lrun += __shfl_xor(lrun, 16);
  lrun += __shfl_xor(lrun, 32);
  float linv[4];
#pragma unroll
  for (int i = 0; i < 4; i++) linv[i] = 1.f / __shfl(lrun, g * 4 + i);

  int b2 = head >> 4, h = head & 15;
#pragma unroll
  for (int i = 0; i < 4; i++) {
    int n = qt * 64 + wid * 16 + g * 4 + i;
    size_t base = ((size_t)b2 * 2048 + n) * 1024 + h * 64;
#pragma unroll
    for (int nfv = 0; nfv < 4; nfv++)
      O[base + nfv * 16 + li] = (bf16_t)(o[nfv][i] * linv[i]);
  }
}

extern "C" void kernel_launch(void* const* d_in, const int* in_sizes, int n_in,
                              void* d_out, int out_size, void* d_ws, size_t ws_size,
                              hipStream_t stream) {
  const float* x    = (const float*)d_in[0];
  const float* Wqkv = (const float*)d_in[1];
  const float* Wout = (const float*)d_in[2];
  const float* bout = (const float*)d_in[3];
  float* out = (float*)d_out;

  char* ws = (char*)d_ws;
  bf16_t* xb    = (bf16_t*)(ws);                          // 8 MB  [4096][1024]
  bf16_t* wqkvT = (bf16_t*)(ws + ((size_t)8  << 20));     // 6 MB  [3072][1024]
  bf16_t* woutT = (bf16_t*)(ws + ((size_t)14 << 20));     // 2 MB  [1024][1024]
  bf16_t* qw    = (bf16_t*)(ws + ((size_t)16 << 20));     // 8 MB  [32][2048][64]
  bf16_t* kw    = (bf16_t*)(ws + ((size_t)24 << 20));     // 8 MB
  bf16_t* vw    = (bf16_t*)(ws + ((size_t)32 << 20));     // 8 MB
  bf16_t* vtw   = (bf16_t*)(ws + ((size_t)40 << 20));     // 8 MB  [32][64][2048]
  bf16_t* ow    = (bf16_t*)(ws + ((size_t)48 << 20));     // 8 MB  [4096][1024]

  k_conv_x<<<2048, 256, 0, stream>>>(x, xb);
  k_transpose_w<<<dim3(96, 32), 256, 0, stream>>>(Wqkv, wqkvT, 1024, 3072);
  k_transpose_w<<<dim3(32, 32), 256, 0, stream>>>(Wout, woutT, 1024, 1024);
  k_gemm<0><<<dim3(32, 24), 256, 0, stream>>>(xb, wqkvT, 1024, qw, kw, vw,
                                              nullptr, nullptr, 0);
  k_vtrans<<<1024, 256, 0, stream>>>(vw, vtw);
  k_flash<<<1024, 256, 0, stream>>>(qw, kw, vtw, ow);
  k_gemm<1><<<dim3(32, 8), 256, 0, stream>>>(ow, woutT, 1024,
                                             nullptr, nullptr, nullptr,
                                             bout, out, 1024);
}

// Round 5
// 125.150 us; speedup vs baseline: 1.5927x; 1.0312x over previous
//
#include <hip/hip_runtime.h>
#include <cstdint>

typedef __bf16 bf16_t;
typedef __bf16 bf16x8 __attribute__((ext_vector_type(8)));
typedef float  f32x4  __attribute__((ext_vector_type(4)));
typedef uint32_t u32x4 __attribute__((ext_vector_type(4)));

#define MFMA16(a,b,c) __builtin_amdgcn_mfma_f32_16x16x32_bf16((a),(b),(c),0,0,0)

__device__ __forceinline__ void gload_lds16(const bf16_t* g, bf16_t* l) {
  __builtin_amdgcn_global_load_lds(
      (const __attribute__((address_space(1))) unsigned int*)g,
      (__attribute__((address_space(3))) unsigned int*)l,
      16, 0, 0);
}

__device__ __forceinline__ uint32_t cvt_pk_bf16(float lo, float hi) {
  uint32_t r;
  asm("v_cvt_pk_bf16_f32 %0, %1, %2" : "=v"(r) : "v"(lo), "v"(hi));
  return r;
}

// ---------------- convert x (f32) -> bf16 ----------------
__global__ void k_conv_x(const float* __restrict__ x, bf16_t* __restrict__ xb) {
  int i = blockIdx.x * blockDim.x + threadIdx.x;
  const float4* p = reinterpret_cast<const float4*>(x) + (size_t)i * 2;
  float4 a = p[0], b = p[1];
  bf16x8 v;
  v[0]=(bf16_t)a.x; v[1]=(bf16_t)a.y; v[2]=(bf16_t)a.z; v[3]=(bf16_t)a.w;
  v[4]=(bf16_t)b.x; v[5]=(bf16_t)b.y; v[6]=(bf16_t)b.z; v[7]=(bf16_t)b.w;
  *reinterpret_cast<bf16x8*>(xb + (size_t)i * 8) = v;
}

// ---------------- transpose-convert W [K][N] f32 -> WT [N][K] bf16 ----------------
__global__ void k_transpose_w(const float* __restrict__ W, bf16_t* __restrict__ WT,
                              int K, int N) {
  __shared__ float tile[32][33];
  int n0 = blockIdx.x * 32, k0 = blockIdx.y * 32;
  int c = threadIdx.x & 31, r8 = threadIdx.x >> 5;
#pragma unroll
  for (int rr = 0; rr < 4; rr++) {
    int r = r8 + rr * 8;
    tile[r][c] = W[(size_t)(k0 + r) * N + n0 + c];
  }
  __syncthreads();
#pragma unroll
  for (int rr = 0; rr < 4; rr++) {
    int r = r8 + rr * 8;
    WT[(size_t)(n0 + r) * K + k0 + c] = (bf16_t)tile[c][r];
  }
}

// ---------------- transpose V [BH][2048][64] -> VT [BH][64][2048] (bf16) ----------------
__global__ void k_vtrans(const bf16_t* __restrict__ V, bf16_t* __restrict__ VT) {
  __shared__ bf16_t t[64 * 72];
  int bi = blockIdx.x;
  int head = bi >> 5, kt = bi & 31;
  int tid = threadIdx.x;
  const bf16_t* src = V + (size_t)head * 131072 + (size_t)kt * 64 * 64;
#pragma unroll
  for (int j = 0; j < 2; j++) {
    int q = tid + 256 * j;
    int key = q >> 3, part = q & 7;
    bf16x8 v = *reinterpret_cast<const bf16x8*>(src + key * 64 + part * 8);
    *reinterpret_cast<bf16x8*>(&t[key * 72 + part * 8]) = v;
  }
  __syncthreads();
  bf16_t* dst = VT + (size_t)head * 131072 + kt * 64;
#pragma unroll
  for (int j = 0; j < 2; j++) {
    int q = tid + 256 * j;
    int dv = q >> 3, part = q & 7;
    bf16x8 v;
#pragma unroll
    for (int e = 0; e < 8; e++) v[e] = t[(part * 8 + e) * 72 + dv];
    *reinterpret_cast<bf16x8*>(dst + (size_t)dv * 2048 + part * 8) = v;
  }
}

// ---------------- GEMM: A[M][K] bf16 @ BT[N][K] bf16 ----------------
template<int EPI>
__global__ __launch_bounds__(256, 2) void k_gemm(
    const bf16_t* __restrict__ A, const bf16_t* __restrict__ BT, int Klen,
    bf16_t* __restrict__ Qo, bf16_t* __restrict__ Ko, bf16_t* __restrict__ Vo,
    const float* __restrict__ bias, float* __restrict__ Out, int Nout) {
  __shared__ bf16_t As[2][4096];
  __shared__ bf16_t Bs[2][4096];
  int tid = threadIdx.x, lane = tid & 63, wid = tid >> 6;
  int row0 = blockIdx.x * 128, col0 = blockIdx.y * 128;
  int wr = wid >> 1, wc = wid & 1;
  int g = lane >> 4, li = lane & 15;

  f32x4 acc[4][4] = {};

  auto stage = [&](int buf, int kt) {
    int k0 = kt * 32;
#pragma unroll
    for (int j = 0; j < 2; j++) {
      int q = tid + 256 * j;
      int r = q >> 2, part = q & 3;
      gload_lds16(A + (size_t)(row0 + r) * Klen + k0 + part * 8,
                  &As[buf][(wid * 64 + j * 256) * 8]);
    }
#pragma unroll
    for (int j = 0; j < 2; j++) {
      int q = tid + 256 * j;
      int r = q >> 2, part = q & 3;
      gload_lds16(BT + (size_t)(col0 + r) * Klen + k0 + part * 8,
                  &Bs[buf][(wid * 64 + j * 256) * 8]);
    }
  };

  int nk = Klen >> 5;
  stage(0, 0);
  for (int kt = 0; kt < nk; kt++) {
    __syncthreads();
    if (kt + 1 < nk) stage((kt + 1) & 1, kt + 1);
    int buf = kt & 1;
    int kl = g * 8;
    bf16x8 a[4], b[4];
#pragma unroll
    for (int m = 0; m < 4; m++)
      a[m] = *reinterpret_cast<const bf16x8*>(&As[buf][(wr * 64 + m * 16 + li) * 32 + kl]);
#pragma unroll
    for (int n = 0; n < 4; n++)
      b[n] = *reinterpret_cast<const bf16x8*>(&Bs[buf][(wc * 64 + n * 16 + li) * 32 + kl]);
#pragma unroll
    for (int m = 0; m < 4; m++)
#pragma unroll
      for (int n = 0; n < 4; n++)
        acc[m][n] = MFMA16(a[m], b[n], acc[m][n]);
  }

#pragma unroll
  for (int m = 0; m < 4; m++) {
    int rg = row0 + wr * 64 + m * 16 + g * 4;
#pragma unroll
    for (int n = 0; n < 4; n++) {
      int cg = col0 + wc * 64 + n * 16 + li;
#pragma unroll
      for (int i = 0; i < 4; i++) {
        float v = acc[m][n][i];
        int row = rg + i;
        if constexpr (EPI == 0) {
          int t = cg >> 10, h = (cg >> 6) & 15, dk = cg & 63;
          int b2 = row >> 11, nn = row & 2047;
          size_t idx = ((size_t)((b2 << 4) + h) * 2048 + nn) * 64 + dk;
          // Q pre-scaled by 1/sqrt(d_k) * log2(e) so softmax can use exp2
          if (t == 0)      Qo[idx] = (bf16_t)(v * 0.18033688011112042f);
          else if (t == 1) Ko[idx] = (bf16_t)v;
          else             Vo[idx] = (bf16_t)v;
        } else {
          Out[(size_t)row * Nout + cg] = v + bias[cg];
        }
      }
    }
  }
}

// ---------------- flash attention v5 ----------------
// v4 structure (swapped QK^T, lane-local P) plus:
//  - acc init = -mrun  (removes per-tile subs; mrun init 0, defer-vote bounds P<=2^8)
//  - row-sum via ones-MFMA into osum (removes rs adds + epilogue reduce)
//  - max3 tree for pmax
__global__ __launch_bounds__(256, 4) void k_flash(
    const bf16_t* __restrict__ Q, const bf16_t* __restrict__ K,
    const bf16_t* __restrict__ VT, bf16_t* __restrict__ O) {
  __shared__ bf16_t Ks[2][64 * 64];
  __shared__ bf16_t Vs[2][64 * 64];

  // XCD swizzle: grid 1024 = 8 XCDs x 128; XCD x serves heads 4x..4x+3
  int bi = (blockIdx.x & 7) * 128 + (blockIdx.x >> 3);
  int head = bi >> 5, qt = bi & 31;
  int tid = threadIdx.x, lane = tid & 63, wid = tid >> 6;
  int g = lane >> 4, li = lane & 15;

  const bf16_t* Qh = Q + (size_t)head * 131072 + (size_t)qt * 64 * 64;
  const bf16_t* Kh = K + (size_t)head * 131072;
  const bf16_t* Vh = VT + (size_t)head * 131072;

  bf16x8 qf[2];
  {
    const bf16_t* qrow = Qh + (size_t)(wid * 16 + li) * 64;
    qf[0] = *reinterpret_cast<const bf16x8*>(qrow + g * 8);
    qf[1] = *reinterpret_cast<const bf16x8*>(qrow + 32 + g * 8);
  }

  // B-fragment of all-ones (bf16 1.0 = 0x3F80) for the row-sum MFMA
  u32x4 onesw;
  onesw[0] = 0x3F803F80u; onesw[1] = 0x3F803F80u;
  onesw[2] = 0x3F803F80u; onesw[3] = 0x3F803F80u;
  bf16x8 ones = __builtin_bit_cast(bf16x8, onesw);

  f32x4 o[4] = {};
  f32x4 osum = {};                 // rowsum of P, rows g*4+i (matches o rows)
  float mrun = 0.f;                // absolute running max, log2 units

  auto stage = [&](int buf, int t) {
    int kv0 = t * 64;
#pragma unroll
    for (int j = 0; j < 2; j++) {
      int q = tid + 256 * j;
      int key = q >> 3, part = q & 7;
      int sw = (key & 7) ^ (((key >> 3) & 3) << 1);
      gload_lds16(Kh + (size_t)(kv0 + key) * 64 + ((part ^ sw) * 8),
                  &Ks[buf][(wid * 64 + j * 256) * 8]);
    }
#pragma unroll
    for (int j = 0; j < 2; j++) {
      int q = tid + 256 * j;
      int dv = q >> 3, part = q & 7;
      gload_lds16(Vh + (size_t)dv * 2048 + kv0 + ((part ^ (dv & 7)) * 8),
                  &Vs[buf][(wid * 64 + j * 256) * 8]);
    }
  };

  stage(0, 0);
  for (int t = 0; t < 32; t++) {
    __syncthreads();                 // tile t staged; prev reads of buf done
    if (t + 1 < 32) stage((t + 1) & 1, t + 1);
    int buf = t & 1;
    char* KsB = (char*)&Ks[buf][0];
    char* VsB = (char*)&Vs[buf][0];

    // S^T = K · Q^T, accumulator pre-biased with -mrun
    float nm = -mrun;
    f32x4 s[4];
#pragma unroll
    for (int nf = 0; nf < 4; nf++) { s[nf][0]=nm; s[nf][1]=nm; s[nf][2]=nm; s[nf][3]=nm; }
    __builtin_amdgcn_s_setprio(1);
#pragma unroll
    for (int kd = 0; kd < 2; kd++)
#pragma unroll
      for (int nf = 0; nf < 4; nf++) {
        int key = ((li >> 2) << 3) | ((nf & 1) << 2) | (li & 3) | ((nf >> 1) << 5);
        int sw = (key & 7) ^ (((key >> 3) & 3) << 1);
        bf16x8 a = *reinterpret_cast<const bf16x8*>(
            KsB + key * 128 + (((kd * 4 + g) ^ sw) << 4));
        s[nf] = MFMA16(a, qf[kd], s[nf]);
      }
    __builtin_amdgcn_s_setprio(0);

    // pmax (relative to mrun) via max3 tree
    float t0 = fmaxf(fmaxf(s[0][0], s[0][1]), s[0][2]);
    float t1 = fmaxf(fmaxf(s[0][3], s[1][0]), s[1][1]);
    float t2 = fmaxf(fmaxf(s[1][2], s[1][3]), s[2][0]);
    float t3 = fmaxf(fmaxf(s[2][1], s[2][2]), s[2][3]);
    float t4 = fmaxf(fmaxf(s[3][0], s[3][1]), s[3][2]);
    float pmax = fmaxf(fmaxf(fmaxf(t0, t1), fmaxf(t2, t3)), fmaxf(t4, s[3][3]));

    if (!__all(pmax <= 8.f)) {
      // rare: true row max across the 4 g-lanes of this row, rescale state
      float v = pmax;
      v = fmaxf(v, __shfl_xor(v, 16));
      v = fmaxf(v, __shfl_xor(v, 32));
      float d = fmaxf(v, 0.f);
      float sc = __builtin_amdgcn_exp2f(-d);
      mrun += d;
#pragma unroll
      for (int nf = 0; nf < 4; nf++)
#pragma unroll
        for (int i = 0; i < 4; i++) s[nf][i] -= d;
      float osc[4];
#pragma unroll
      for (int i = 0; i < 4; i++) osc[i] = __shfl(sc, g * 4 + i);
#pragma unroll
      for (int nf = 0; nf < 4; nf++)
#pragma unroll
        for (int i = 0; i < 4; i++) o[nf][i] *= osc[i];
#pragma unroll
      for (int i = 0; i < 4; i++) osum[i] *= osc[i];
    }

    // P = exp2(s)  (already relative to mrun)
#pragma unroll
    for (int nf = 0; nf < 4; nf++)
#pragma unroll
      for (int i = 0; i < 4; i++)
        s[nf][i] = __builtin_amdgcn_exp2f(s[nf][i]);

    // pack P into PV A-fragments (lane-local by key_of construction)
    u32x4 w0, w1;
    w0[0] = cvt_pk_bf16(s[0][0], s[0][1]);
    w0[1] = cvt_pk_bf16(s[0][2], s[0][3]);
    w0[2] = cvt_pk_bf16(s[1][0], s[1][1]);
    w0[3] = cvt_pk_bf16(s[1][2], s[1][3]);
    w1[0] = cvt_pk_bf16(s[2][0], s[2][1]);
    w1[1] = cvt_pk_bf16(s[2][2], s[2][3]);
    w1[2] = cvt_pk_bf16(s[3][0], s[3][1]);
    w1[3] = cvt_pk_bf16(s[3][2], s[3][3]);
    bf16x8 pa0 = __builtin_bit_cast(bf16x8, w0);
    bf16x8 pa1 = __builtin_bit_cast(bf16x8, w1);

    // O += P V ; row-sum via ones-MFMA (rowsum replicated across cols)
    __builtin_amdgcn_s_setprio(1);
    osum = MFMA16(pa0, ones, osum);
    osum = MFMA16(pa1, ones, osum);
#pragma unroll
    for (int nfv = 0; nfv < 4; nfv++) {
      int dv = nfv * 16 + li;
      bf16x8 b0 = *reinterpret_cast<const bf16x8*>(
          VsB + dv * 128 + ((g * 16) ^ ((dv & 7) << 4)));
      o[nfv] = MFMA16(pa0, b0, o[nfv]);
      bf16x8 b1 = *reinterpret_cast<const bf16x8*>(
          VsB + dv * 128 + ((64 + g * 16) ^ ((dv & 7) << 4)));
      o[nfv] = MFMA16(pa1, b1, o[nfv]);
    }
    __builtin_amdgcn_s_setprio(0);
  }

  // epilogue: osum[i] is the row-sum for output row g*4+i — no reduction needed
  int b2 = head >> 4, h = head & 15;
#pragma unroll
  for (int i = 0; i < 4; i++) {
    float inv = 1.f / osum[i];
    int n = qt * 64 + wid * 16 + g * 4 + i;
    size_t base = ((size_t)b2 * 2048 + n) * 1024 + h * 64;
#pragma unroll
    for (int nfv = 0; nfv < 4; nfv++)
      O[base + nfv * 16 + li] = (bf16_t)(o[nfv][i] * inv);
  }
}

extern "C" void kernel_launch(void* const* d_in, const int* in_sizes, int n_in,
                              void* d_out, int out_size, void* d_ws, size_t ws_size,
                              hipStream_t stream) {
  const float* x    = (const float*)d_in[0];
  const float* Wqkv = (const float*)d_in[1];
  const float* Wout = (const float*)d_in[2];
  const float* bout = (const float*)d_in[3];
  float* out = (float*)d_out;

  char* ws = (char*)d_ws;
  bf16_t* xb    = (bf16_t*)(ws);                          // 8 MB  [4096][1024]
  bf16_t* wqkvT = (bf16_t*)(ws + ((size_t)8  << 20));     // 6 MB  [3072][1024]
  bf16_t* woutT = (bf16_t*)(ws + ((size_t)14 << 20));     // 2 MB  [1024][1024]
  bf16_t* qw    = (bf16_t*)(ws + ((size_t)16 << 20));     // 8 MB  [32][2048][64]
  bf16_t* kw    = (bf16_t*)(ws + ((size_t)24 << 20));     // 8 MB
  bf16_t* vw    = (bf16_t*)(ws + ((size_t)32 << 20));     // 8 MB
  bf16_t* vtw   = (bf16_t*)(ws + ((size_t)40 << 20));     // 8 MB  [32][64][2048]
  bf16_t* ow    = (bf16_t*)(ws + ((size_t)48 << 20));     // 8 MB  [4096][1024]

  k_conv_x<<<2048, 256, 0, stream>>>(x, xb);
  k_transpose_w<<<dim3(96, 32), 256, 0, stream>>>(Wqkv, wqkvT, 1024, 3072);
  k_transpose_w<<<dim3(32, 32), 256, 0, stream>>>(Wout, woutT, 1024, 1024);
  k_gemm<0><<<dim3(32, 24), 256, 0, stream>>>(xb, wqkvT, 1024, qw, kw, vw,
                                              nullptr, nullptr, 0);
  k_vtrans<<<1024, 256, 0, stream>>>(vw, vtw);
  k_flash<<<1024, 256, 0, stream>>>(qw, kw, vtw, ow);
  k_gemm<1><<<dim3(32, 8), 256, 0, stream>>>(ow, woutT, 1024,
                                             nullptr, nullptr, nullptr,
                                             bout, out, 1024);
}

// Round 6
// 118.917 us; speedup vs baseline: 1.6761x; 1.0524x over previous
//
#include <hip/hip_runtime.h>
#include <cstdint>

typedef __bf16 bf16_t;
typedef __bf16 bf16x8 __attribute__((ext_vector_type(8)));
typedef float  f32x4  __attribute__((ext_vector_type(4)));
typedef uint32_t u32x4 __attribute__((ext_vector_type(4)));

#define MFMA16(a,b,c) __builtin_amdgcn_mfma_f32_16x16x32_bf16((a),(b),(c),0,0,0)

__device__ __forceinline__ void gload_lds16(const bf16_t* g, bf16_t* l) {
  __builtin_amdgcn_global_load_lds(
      (const __attribute__((address_space(1))) unsigned int*)g,
      (__attribute__((address_space(3))) unsigned int*)l,
      16, 0, 0);
}

__device__ __forceinline__ uint32_t cvt_pk_bf16(float lo, float hi) {
  uint32_t r;
  asm("v_cvt_pk_bf16_f32 %0, %1, %2" : "=v"(r) : "v"(lo), "v"(hi));
  return r;
}

// ---------------- convert x (f32) -> bf16 ----------------
__global__ void k_conv_x(const float* __restrict__ x, bf16_t* __restrict__ xb) {
  int i = blockIdx.x * blockDim.x + threadIdx.x;
  const float4* p = reinterpret_cast<const float4*>(x) + (size_t)i * 2;
  float4 a = p[0], b = p[1];
  bf16x8 v;
  v[0]=(bf16_t)a.x; v[1]=(bf16_t)a.y; v[2]=(bf16_t)a.z; v[3]=(bf16_t)a.w;
  v[4]=(bf16_t)b.x; v[5]=(bf16_t)b.y; v[6]=(bf16_t)b.z; v[7]=(bf16_t)b.w;
  *reinterpret_cast<bf16x8*>(xb + (size_t)i * 8) = v;
}

// ---------------- transpose-convert W [K][N] f32 -> WT [N][K] bf16 ----------------
__global__ void k_transpose_w(const float* __restrict__ W, bf16_t* __restrict__ WT,
                              int K, int N) {
  __shared__ float tile[32][33];
  int n0 = blockIdx.x * 32, k0 = blockIdx.y * 32;
  int c = threadIdx.x & 31, r8 = threadIdx.x >> 5;
#pragma unroll
  for (int rr = 0; rr < 4; rr++) {
    int r = r8 + rr * 8;
    tile[r][c] = W[(size_t)(k0 + r) * N + n0 + c];
  }
  __syncthreads();
#pragma unroll
  for (int rr = 0; rr < 4; rr++) {
    int r = r8 + rr * 8;
    WT[(size_t)(n0 + r) * K + k0 + c] = (bf16_t)tile[c][r];
  }
}

// ---------------- transpose V [BH][2048][64] -> VT [BH][64][2048] (bf16) ----------------
__global__ void k_vtrans(const bf16_t* __restrict__ V, bf16_t* __restrict__ VT) {
  __shared__ bf16_t t[64 * 72];
  int bi = blockIdx.x;
  int head = bi >> 5, kt = bi & 31;
  int tid = threadIdx.x;
  const bf16_t* src = V + (size_t)head * 131072 + (size_t)kt * 64 * 64;
#pragma unroll
  for (int j = 0; j < 2; j++) {
    int q = tid + 256 * j;
    int key = q >> 3, part = q & 7;
    bf16x8 v = *reinterpret_cast<const bf16x8*>(src + key * 64 + part * 8);
    *reinterpret_cast<bf16x8*>(&t[key * 72 + part * 8]) = v;
  }
  __syncthreads();
  bf16_t* dst = VT + (size_t)head * 131072 + kt * 64;
#pragma unroll
  for (int j = 0; j < 2; j++) {
    int q = tid + 256 * j;
    int dv = q >> 3, part = q & 7;
    bf16x8 v;
#pragma unroll
    for (int e = 0; e < 8; e++) v[e] = t[(part * 8 + e) * 72 + dv];
    *reinterpret_cast<bf16x8*>(dst + (size_t)dv * 2048 + part * 8) = v;
  }
}

// ---------------- GEMM: A[M][K] bf16 @ BT[N][K] bf16, M-tile templated ----------------
// EPI 0: scatter into Q (x0.125*log2e), K, V per-head layouts.  EPI 1: f32 out + bias.
template<int EPI, int MT>
__global__ __launch_bounds__(256, 2) void k_gemm(
    const bf16_t* __restrict__ A, const bf16_t* __restrict__ BT, int Klen,
    bf16_t* __restrict__ Qo, bf16_t* __restrict__ Ko, bf16_t* __restrict__ Vo,
    const float* __restrict__ bias, float* __restrict__ Out, int Nout) {
  constexpr int WM = MT / 2;       // rows per wave
  constexpr int MF = WM / 16;      // m fragments per wave
  __shared__ bf16_t As[2][MT * 32];
  __shared__ bf16_t Bs[2][4096];
  int tid = threadIdx.x, lane = tid & 63, wid = tid >> 6;
  int row0 = blockIdx.x * MT, col0 = blockIdx.y * 128;
  int wr = wid >> 1, wc = wid & 1;
  int g = lane >> 4, li = lane & 15;

  f32x4 acc[MF][4] = {};

  auto stage = [&](int buf, int kt) {
    int k0 = kt * 32;
#pragma unroll
    for (int j = 0; j < MT / 64; j++) {
      int q = tid + 256 * j;
      int r = q >> 2, part = q & 3;
      gload_lds16(A + (size_t)(row0 + r) * Klen + k0 + part * 8,
                  &As[buf][q * 8]);
    }
#pragma unroll
    for (int j = 0; j < 2; j++) {
      int q = tid + 256 * j;
      int r = q >> 2, part = q & 3;
      gload_lds16(BT + (size_t)(col0 + r) * Klen + k0 + part * 8,
                  &Bs[buf][q * 8]);
    }
  };

  int nk = Klen >> 5;
  stage(0, 0);
  for (int kt = 0; kt < nk; kt++) {
    __syncthreads();
    if (kt + 1 < nk) stage((kt + 1) & 1, kt + 1);
    int buf = kt & 1;
    int kl = g * 8;
    bf16x8 a[MF], b[4];
#pragma unroll
    for (int m = 0; m < MF; m++)
      a[m] = *reinterpret_cast<const bf16x8*>(&As[buf][(wr * WM + m * 16 + li) * 32 + kl]);
#pragma unroll
    for (int n = 0; n < 4; n++)
      b[n] = *reinterpret_cast<const bf16x8*>(&Bs[buf][(wc * 64 + n * 16 + li) * 32 + kl]);
#pragma unroll
    for (int m = 0; m < MF; m++)
#pragma unroll
      for (int n = 0; n < 4; n++)
        acc[m][n] = MFMA16(a[m], b[n], acc[m][n]);
  }

#pragma unroll
  for (int m = 0; m < MF; m++) {
    int rg = row0 + wr * WM + m * 16 + g * 4;
#pragma unroll
    for (int n = 0; n < 4; n++) {
      int cg = col0 + wc * 64 + n * 16 + li;
#pragma unroll
      for (int i = 0; i < 4; i++) {
        float v = acc[m][n][i];
        int row = rg + i;
        if constexpr (EPI == 0) {
          int t = cg >> 10, h = (cg >> 6) & 15, dk = cg & 63;
          int b2 = row >> 11, nn = row & 2047;
          size_t idx = ((size_t)((b2 << 4) + h) * 2048 + nn) * 64 + dk;
          // Q pre-scaled by 1/sqrt(d_k) * log2(e) so softmax can use exp2
          if (t == 0)      Qo[idx] = (bf16_t)(v * 0.18033688011112042f);
          else if (t == 1) Ko[idx] = (bf16_t)v;
          else             Vo[idx] = (bf16_t)v;
        } else {
          Out[(size_t)row * Nout + cg] = v + bias[cg];
        }
      }
    }
  }
}

// ---------------- flash attention v6 ----------------
// v5 softmax machinery, but 32 q-rows PER WAVE (two 16-row groups rg=0,1):
// K A-frags and V B-frags are read from LDS once and reused for both groups,
// halving LDS read traffic per unit of work (the v5 bottleneck).
// QBLK=128, 4 waves, grid 512 (16 q-tiles x 32 heads), 2 blocks/CU.
__global__ __launch_bounds__(256, 2) void k_flash(
    const bf16_t* __restrict__ Q, const bf16_t* __restrict__ K,
    const bf16_t* __restrict__ VT, bf16_t* __restrict__ O) {
  __shared__ bf16_t Ks[2][64 * 64];
  __shared__ bf16_t Vs[2][64 * 64];

  // XCD swizzle: grid 512 = 8 XCDs x 64; XCD x serves heads 4x..4x+3
  int bi = (blockIdx.x & 7) * 64 + (blockIdx.x >> 3);
  int head = bi >> 4, qt = bi & 15;
  int tid = threadIdx.x, lane = tid & 63, wid = tid >> 6;
  int g = lane >> 4, li = lane & 15;

  const bf16_t* Qh = Q + (size_t)head * 131072 + (size_t)qt * 128 * 64;
  const bf16_t* Kh = K + (size_t)head * 131072;
  const bf16_t* Vh = VT + (size_t)head * 131072;

  // Q B-fragments for the wave's two 16-row groups
  bf16x8 qf[2][2];
#pragma unroll
  for (int rg = 0; rg < 2; rg++) {
    const bf16_t* qrow = Qh + (size_t)(wid * 32 + rg * 16 + li) * 64;
    qf[rg][0] = *reinterpret_cast<const bf16x8*>(qrow + g * 8);
    qf[rg][1] = *reinterpret_cast<const bf16x8*>(qrow + 32 + g * 8);
  }

  // B-fragment of all-ones (bf16 1.0 = 0x3F80) for the row-sum MFMA
  u32x4 onesw;
  onesw[0] = 0x3F803F80u; onesw[1] = 0x3F803F80u;
  onesw[2] = 0x3F803F80u; onesw[3] = 0x3F803F80u;
  bf16x8 ones = __builtin_bit_cast(bf16x8, onesw);

  f32x4 o[2][4] = {};
  f32x4 osum[2] = {};
  float mrun[2] = {0.f, 0.f};      // absolute running max, log2 units

  auto stage = [&](int buf, int t) {
    int kv0 = t * 64;
#pragma unroll
    for (int j = 0; j < 2; j++) {
      int q = tid + 256 * j;
      int key = q >> 3, part = q & 7;
      int sw = (key & 7) ^ (((key >> 3) & 3) << 1);
      gload_lds16(Kh + (size_t)(kv0 + key) * 64 + ((part ^ sw) * 8),
                  &Ks[buf][(tid + j * 256) * 8]);
    }
#pragma unroll
    for (int j = 0; j < 2; j++) {
      int q = tid + 256 * j;
      int dv = q >> 3, part = q & 7;
      gload_lds16(Vh + (size_t)dv * 2048 + kv0 + ((part ^ (dv & 7)) * 8),
                  &Vs[buf][(tid + j * 256) * 8]);
    }
  };

  stage(0, 0);
  for (int t = 0; t < 32; t++) {
    __syncthreads();                 // tile t staged; prev reads of buf done
    if (t + 1 < 32) stage((t + 1) & 1, t + 1);
    int buf = t & 1;
    char* KsB = (char*)&Ks[buf][0];
    char* VsB = (char*)&Vs[buf][0];

    // K A-fragments: read ONCE, reused for both row groups
    bf16x8 ka[2][4];
#pragma unroll
    for (int kd = 0; kd < 2; kd++)
#pragma unroll
      for (int nf = 0; nf < 4; nf++) {
        int key = ((li >> 2) << 3) | ((nf & 1) << 2) | (li & 3) | ((nf >> 1) << 5);
        int sw = (key & 7) ^ (((key >> 3) & 3) << 1);
        ka[kd][nf] = *reinterpret_cast<const bf16x8*>(
            KsB + key * 128 + (((kd * 4 + g) ^ sw) << 4));
      }

    // S^T = K · Q^T, accumulators pre-biased with -mrun[rg]
    f32x4 s[2][4];
#pragma unroll
    for (int rg = 0; rg < 2; rg++) {
      float nm = -mrun[rg];
#pragma unroll
      for (int nf = 0; nf < 4; nf++) {
        s[rg][nf][0] = nm; s[rg][nf][1] = nm; s[rg][nf][2] = nm; s[rg][nf][3] = nm;
      }
    }
    __builtin_amdgcn_s_setprio(1);
#pragma unroll
    for (int kd = 0; kd < 2; kd++)
#pragma unroll
      for (int nf = 0; nf < 4; nf++) {
        s[0][nf] = MFMA16(ka[kd][nf], qf[0][kd], s[0][nf]);
        s[1][nf] = MFMA16(ka[kd][nf], qf[1][kd], s[1][nf]);
      }
    __builtin_amdgcn_s_setprio(0);

    // pmax per row group (relative to mrun) via max3-friendly tree
    float pmax[2];
#pragma unroll
    for (int rg = 0; rg < 2; rg++) {
      float t0 = fmaxf(fmaxf(s[rg][0][0], s[rg][0][1]), s[rg][0][2]);
      float t1 = fmaxf(fmaxf(s[rg][0][3], s[rg][1][0]), s[rg][1][1]);
      float t2 = fmaxf(fmaxf(s[rg][1][2], s[rg][1][3]), s[rg][2][0]);
      float t3 = fmaxf(fmaxf(s[rg][2][1], s[rg][2][2]), s[rg][2][3]);
      float t4 = fmaxf(fmaxf(s[rg][3][0], s[rg][3][1]), s[rg][3][2]);
      pmax[rg] = fmaxf(fmaxf(fmaxf(t0, t1), fmaxf(t2, t3)), fmaxf(t4, s[rg][3][3]));
    }

    bool ok = (pmax[0] <= 8.f) & (pmax[1] <= 8.f);
    if (!__all(ok)) {
      // rare: true row max across the 4 g-lanes, rescale state per group
#pragma unroll
      for (int rg = 0; rg < 2; rg++) {
        float v = pmax[rg];
        v = fmaxf(v, __shfl_xor(v, 16));
        v = fmaxf(v, __shfl_xor(v, 32));
        float d = fmaxf(v, 0.f);
        float sc = __builtin_amdgcn_exp2f(-d);
        mrun[rg] += d;
#pragma unroll
        for (int nf = 0; nf < 4; nf++)
#pragma unroll
          for (int i = 0; i < 4; i++) s[rg][nf][i] -= d;
        float osc[4];
#pragma unroll
        for (int i = 0; i < 4; i++) osc[i] = __shfl(sc, g * 4 + i);
#pragma unroll
        for (int nf = 0; nf < 4; nf++)
#pragma unroll
          for (int i = 0; i < 4; i++) o[rg][nf][i] *= osc[i];
#pragma unroll
        for (int i = 0; i < 4; i++) osum[rg][i] *= osc[i];
      }
    }

    // P = exp2(s); pack into PV A-fragments (lane-local by key_of construction)
    bf16x8 pa[2][2];
#pragma unroll
    for (int rg = 0; rg < 2; rg++) {
#pragma unroll
      for (int nf = 0; nf < 4; nf++)
#pragma unroll
        for (int i = 0; i < 4; i++)
          s[rg][nf][i] = __builtin_amdgcn_exp2f(s[rg][nf][i]);
      u32x4 w0, w1;
      w0[0] = cvt_pk_bf16(s[rg][0][0], s[rg][0][1]);
      w0[1] = cvt_pk_bf16(s[rg][0][2], s[rg][0][3]);
      w0[2] = cvt_pk_bf16(s[rg][1][0], s[rg][1][1]);
      w0[3] = cvt_pk_bf16(s[rg][1][2], s[rg][1][3]);
      w1[0] = cvt_pk_bf16(s[rg][2][0], s[rg][2][1]);
      w1[1] = cvt_pk_bf16(s[rg][2][2], s[rg][2][3]);
      w1[2] = cvt_pk_bf16(s[rg][3][0], s[rg][3][1]);
      w1[3] = cvt_pk_bf16(s[rg][3][2], s[rg][3][3]);
      pa[rg][0] = __builtin_bit_cast(bf16x8, w0);
      pa[rg][1] = __builtin_bit_cast(bf16x8, w1);
    }

    // O += P V ; row-sums via ones-MFMA.  V B-frags read once, used by both groups.
    __builtin_amdgcn_s_setprio(1);
    osum[0] = MFMA16(pa[0][0], ones, osum[0]);
    osum[0] = MFMA16(pa[0][1], ones, osum[0]);
    osum[1] = MFMA16(pa[1][0], ones, osum[1]);
    osum[1] = MFMA16(pa[1][1], ones, osum[1]);
#pragma unroll
    for (int nfv = 0; nfv < 4; nfv++) {
      int dv = nfv * 16 + li;
      bf16x8 b0 = *reinterpret_cast<const bf16x8*>(
          VsB + dv * 128 + ((g * 16) ^ ((dv & 7) << 4)));
      bf16x8 b1 = *reinterpret_cast<const bf16x8*>(
          VsB + dv * 128 + ((64 + g * 16) ^ ((dv & 7) << 4)));
      o[0][nfv] = MFMA16(pa[0][0], b0, o[0][nfv]);
      o[0][nfv] = MFMA16(pa[0][1], b1, o[0][nfv]);
      o[1][nfv] = MFMA16(pa[1][0], b0, o[1][nfv]);
      o[1][nfv] = MFMA16(pa[1][1], b1, o[1][nfv]);
    }
    __builtin_amdgcn_s_setprio(0);
  }

  // epilogue: osum[rg][i] is the row-sum for output row rg*16 + g*4 + i
  int b2 = head >> 4, h = head & 15;
#pragma unroll
  for (int rg = 0; rg < 2; rg++) {
#pragma unroll
    for (int i = 0; i < 4; i++) {
      float inv = 1.f / osum[rg][i];
      int n = qt * 128 + wid * 32 + rg * 16 + g * 4 + i;
      size_t base = ((size_t)b2 * 2048 + n) * 1024 + h * 64;
#pragma unroll
      for (int nfv = 0; nfv < 4; nfv++)
        O[base + nfv * 16 + li] = (bf16_t)(o[rg][nfv][i] * inv);
    }
  }
}

extern "C" void kernel_launch(void* const* d_in, const int* in_sizes, int n_in,
                              void* d_out, int out_size, void* d_ws, size_t ws_size,
                              hipStream_t stream) {
  const float* x    = (const float*)d_in[0];
  const float* Wqkv = (const float*)d_in[1];
  const float* Wout = (const float*)d_in[2];
  const float* bout = (const float*)d_in[3];
  float* out = (float*)d_out;

  char* ws = (char*)d_ws;
  bf16_t* xb    = (bf16_t*)(ws);                          // 8 MB  [4096][1024]
  bf16_t* wqkvT = (bf16_t*)(ws + ((size_t)8  << 20));     // 6 MB  [3072][1024]
  bf16_t* woutT = (bf16_t*)(ws + ((size_t)14 << 20));     // 2 MB  [1024][1024]
  bf16_t* qw    = (bf16_t*)(ws + ((size_t)16 << 20));     // 8 MB  [32][2048][64]
  bf16_t* kw    = (bf16_t*)(ws + ((size_t)24 << 20));     // 8 MB
  bf16_t* vw    = (bf16_t*)(ws + ((size_t)32 << 20));     // 8 MB
  bf16_t* vtw   = (bf16_t*)(ws + ((size_t)40 << 20));     // 8 MB  [32][64][2048]
  bf16_t* ow    = (bf16_t*)(ws + ((size_t)48 << 20));     // 8 MB  [4096][1024]

  k_conv_x<<<2048, 256, 0, stream>>>(x, xb);
  k_transpose_w<<<dim3(96, 32), 256, 0, stream>>>(Wqkv, wqkvT, 1024, 3072);
  k_transpose_w<<<dim3(32, 32), 256, 0, stream>>>(Wout, woutT, 1024, 1024);
  k_gemm<0,128><<<dim3(32, 24), 256, 0, stream>>>(xb, wqkvT, 1024, qw, kw, vw,
                                                  nullptr, nullptr, 0);
  k_vtrans<<<1024, 256, 0, stream>>>(vw, vtw);
  k_flash<<<512, 256, 0, stream>>>(qw, kw, vtw, ow);
  k_gemm<1,64><<<dim3(64, 8), 256, 0, stream>>>(ow, woutT, 1024,
                                                nullptr, nullptr, nullptr,
                                                bout, out, 1024);
}

// Round 7
// 117.609 us; speedup vs baseline: 1.6948x; 1.0111x over previous
//
#include <hip/hip_runtime.h>
#include <cstdint>

typedef __bf16 bf16_t;
typedef __bf16 bf16x8 __attribute__((ext_vector_type(8)));
typedef float  f32x4  __attribute__((ext_vector_type(4)));
typedef uint32_t u32x4 __attribute__((ext_vector_type(4)));

#define MFMA16(a,b,c) __builtin_amdgcn_mfma_f32_16x16x32_bf16((a),(b),(c),0,0,0)

__device__ __forceinline__ void gload_lds16(const bf16_t* g, bf16_t* l) {
  __builtin_amdgcn_global_load_lds(
      (const __attribute__((address_space(1))) unsigned int*)g,
      (__attribute__((address_space(3))) unsigned int*)l,
      16, 0, 0);
}

__device__ __forceinline__ uint32_t cvt_pk_bf16(float lo, float hi) {
  uint32_t r;
  asm("v_cvt_pk_bf16_f32 %0, %1, %2" : "=v"(r) : "v"(lo), "v"(hi));
  return r;
}

// ---------------- convert x (f32) -> bf16 ----------------
__global__ void k_conv_x(const float* __restrict__ x, bf16_t* __restrict__ xb) {
  int i = blockIdx.x * blockDim.x + threadIdx.x;
  const float4* p = reinterpret_cast<const float4*>(x) + (size_t)i * 2;
  float4 a = p[0], b = p[1];
  bf16x8 v;
  v[0]=(bf16_t)a.x; v[1]=(bf16_t)a.y; v[2]=(bf16_t)a.z; v[3]=(bf16_t)a.w;
  v[4]=(bf16_t)b.x; v[5]=(bf16_t)b.y; v[6]=(bf16_t)b.z; v[7]=(bf16_t)b.w;
  *reinterpret_cast<bf16x8*>(xb + (size_t)i * 8) = v;
}

// ---------------- transpose-convert W [K][N] f32 -> WT [N][K] bf16 ----------------
__global__ void k_transpose_w(const float* __restrict__ W, bf16_t* __restrict__ WT,
                              int K, int N) {
  __shared__ float tile[32][33];
  int n0 = blockIdx.x * 32, k0 = blockIdx.y * 32;
  int c = threadIdx.x & 31, r8 = threadIdx.x >> 5;
#pragma unroll
  for (int rr = 0; rr < 4; rr++) {
    int r = r8 + rr * 8;
    tile[r][c] = W[(size_t)(k0 + r) * N + n0 + c];
  }
  __syncthreads();
#pragma unroll
  for (int rr = 0; rr < 4; rr++) {
    int r = r8 + rr * 8;
    WT[(size_t)(n0 + r) * K + k0 + c] = (bf16_t)tile[c][r];
  }
}

// ---------------- transpose V [BH][2048][64] -> VT [BH][64][2048] (bf16) ----------------
__global__ void k_vtrans(const bf16_t* __restrict__ V, bf16_t* __restrict__ VT) {
  __shared__ bf16_t t[64 * 72];
  int bi = blockIdx.x;
  int head = bi >> 5, kt = bi & 31;
  int tid = threadIdx.x;
  const bf16_t* src = V + (size_t)head * 131072 + (size_t)kt * 64 * 64;
#pragma unroll
  for (int j = 0; j < 2; j++) {
    int q = tid + 256 * j;
    int key = q >> 3, part = q & 7;
    bf16x8 v = *reinterpret_cast<const bf16x8*>(src + key * 64 + part * 8);
    *reinterpret_cast<bf16x8*>(&t[key * 72 + part * 8]) = v;
  }
  __syncthreads();
  bf16_t* dst = VT + (size_t)head * 131072 + kt * 64;
#pragma unroll
  for (int j = 0; j < 2; j++) {
    int q = tid + 256 * j;
    int dv = q >> 3, part = q & 7;
    bf16x8 v;
#pragma unroll
    for (int e = 0; e < 8; e++) v[e] = t[(part * 8 + e) * 72 + dv];
    *reinterpret_cast<bf16x8*>(dst + (size_t)dv * 2048 + part * 8) = v;
  }
}

// ---------------- 256x256 8-phase QKV GEMM (T2+T3+T4+T5) ----------------
// A[4096][1024] bf16 @ BT[3072][1024] bf16 -> scatter Q(xscale)/K/V per-head.
// 8 waves (2M x 4N), per-wave C = 128x64, BK=64, 2 K-tiles per 8-phase iter.
// LDS 128KB dynamic: A slots [2buf][2half][128][64], B same at +64KB.
// Swizzle: byte-in-row = (g*16 + kk*64) ^ ((row&7)<<4); staging pre-swizzles
// the GLOBAL source (linear gload_lds dest) - both-sides-or-neither.
#define BAR()    __builtin_amdgcn_s_barrier()
#define LGKM0()  do { asm volatile("s_waitcnt lgkmcnt(0)" ::: "memory"); \
                      __builtin_amdgcn_sched_barrier(0); } while (0)
#define VMW(n)   asm volatile("s_waitcnt vmcnt(" #n ")" ::: "memory")

#define LDA(buf, mh) do {                                                   \
    char* base_ = L + ((buf) * 2 + wr) * 16384;                             \
    _Pragma("unroll")                                                       \
    for (int mf = 0; mf < 4; mf++) {                                        \
      int r_ = ((mh) * 64 + mf * 16 + li) * 128;                            \
      a[mf][0] = *reinterpret_cast<const bf16x8*>(base_ + r_ + aoff0);      \
      a[mf][1] = *reinterpret_cast<const bf16x8*>(base_ + r_ + aoff1);      \
    } } while (0)

#define LDB(buf, nh) do {                                                   \
    char* base_ = L + 65536 + ((buf) * 2 + (wc >> 1)) * 16384;              \
    _Pragma("unroll")                                                       \
    for (int nf = 0; nf < 2; nf++) {                                        \
      int r_ = (((wc & 1) * 64) + (nh) * 32 + nf * 16 + li) * 128;          \
      b[nh][nf][0] = *reinterpret_cast<const bf16x8*>(base_ + r_ + aoff0);  \
      b[nh][nf][1] = *reinterpret_cast<const bf16x8*>(base_ + r_ + aoff1);  \
    } } while (0)

#define QUAD(mh, nh) do {                                                   \
    __builtin_amdgcn_s_setprio(1);                                          \
    _Pragma("unroll")                                                       \
    for (int mf = 0; mf < 4; mf++)                                          \
      _Pragma("unroll")                                                     \
      for (int nf = 0; nf < 2; nf++) {                                      \
        acc[mh][nh][mf][nf] = MFMA16(a[mf][0], b[nh][nf][0], acc[mh][nh][mf][nf]); \
        acc[mh][nh][mf][nf] = MFMA16(a[mf][1], b[nh][nf][1], acc[mh][nh][mf][nf]); \
      }                                                                      \
    __builtin_amdgcn_s_setprio(0); } while (0)

__global__ __launch_bounds__(512, 2) void k_gemm_qkv(
    const bf16_t* __restrict__ A, const bf16_t* __restrict__ BT, int Klen,
    bf16_t* __restrict__ Qo, bf16_t* __restrict__ Ko, bf16_t* __restrict__ Vo) {
  extern __shared__ bf16_t lds[];
  int tid = threadIdx.x, lane = tid & 63, wid = tid >> 6;
  int wr = wid >> 2, wc = wid & 3;
  int g = lane >> 4, li = lane & 15;

  // XCD swizzle: 192 blocks = 8 XCDs x 24 contiguous (each XCD ~2 B-panels)
  int lin = (blockIdx.x & 7) * 24 + (blockIdx.x >> 3);
  int bx = lin & 15, by = lin >> 4;
  int row0 = bx * 256, col0 = by * 256;

  char* L = (char*)lds;
  int sw    = (li & 7) << 4;
  int aoff0 = (g * 16) ^ sw;
  int aoff1 = (g * 16 + 64) ^ sw;
  int soff_e = ((((tid & 7) * 16) ^ (((tid >> 3) & 7) << 4))) >> 1;

  f32x4 acc[2][2][4][2] = {};
  bf16x8 a[4][2], b[2][2][2];

  int nk = Klen >> 6;   // 16 K-tiles of 64

  auto stageA = [&](int h, int kt) {
    int rb = row0 + h * 128 + (tid >> 3);
    const bf16_t* src = A + (size_t)rb * Klen + kt * 64 + soff_e;
    bf16_t* dst = lds + ((kt & 1) * 2 + h) * 8192 + tid * 8;
    gload_lds16(src, dst);
    gload_lds16(src + (size_t)64 * Klen, dst + 4096);
  };
  auto stageB = [&](int h, int kt) {
    int rb = col0 + h * 128 + (tid >> 3);
    const bf16_t* src = BT + (size_t)rb * Klen + kt * 64 + soff_e;
    bf16_t* dst = lds + 32768 + ((kt & 1) * 2 + h) * 8192 + tid * 8;
    gload_lds16(src, dst);
    gload_lds16(src + (size_t)64 * Klen, dst + 4096);
  };

  // prologue: T0 fully + B of T1 (3 half-tiles ahead at first wait)
  stageA(0, 0); stageA(1, 0); stageB(0, 0); stageB(1, 0);
  stageB(0, 1); stageB(1, 1);
  VMW(4); BAR();

  for (int i = 0; i < nk / 2; i++) {
    int T1 = 2 * i + 1, T2 = 2 * i + 2, T3 = 2 * i + 3;
    bool s2 = T2 < nk, s3 = T3 < nk;
    // ---- K-tile T0 = 2i (buf 0) ----
    // p0
    LDA(0, 0); LDB(0, 0); stageA(0, T1);
    BAR(); LGKM0(); QUAD(0, 0); BAR();
    // p1
    LDB(0, 1); stageA(1, T1);
    BAR(); LGKM0(); QUAD(0, 1); BAR();
    // p2
    LDA(0, 1); if (s2) stageB(0, T2);
    BAR(); LGKM0(); QUAD(1, 0); BAR();
    // p3  (counted wait: T1 must be landed; allow T2's B0,B1 in flight)
    if (s2) stageB(1, T2);
    BAR(); QUAD(1, 1);
    if (s2) { VMW(4); } else { VMW(0); }
    BAR();
    // ---- K-tile T1 = 2i+1 (buf 1) ----
    // p4
    LDA(1, 0); LDB(1, 0); if (s2) stageA(0, T2);
    BAR(); LGKM0(); QUAD(0, 0); BAR();
    // p5
    LDB(1, 1); if (s2) stageA(1, T2);
    BAR(); LGKM0(); QUAD(0, 1); BAR();
    // p6
    LDA(1, 1); if (s3) stageB(0, T3);
    BAR(); LGKM0(); QUAD(1, 0); BAR();
    // p7  (counted wait: T2 must be landed; allow T3's B0,B1 in flight)
    if (s3) stageB(1, T3);
    BAR(); QUAD(1, 1);
    if (s3) { VMW(4); } else { VMW(0); }
    BAR();
  }

  // epilogue: scatter to Q (pre-scaled by 1/sqrt(dk)*log2e), K, V
#pragma unroll
  for (int mh = 0; mh < 2; mh++)
#pragma unroll
    for (int nh = 0; nh < 2; nh++)
#pragma unroll
      for (int mf = 0; mf < 4; mf++)
#pragma unroll
        for (int nf = 0; nf < 2; nf++) {
          int rg = row0 + wr * 128 + mh * 64 + mf * 16 + g * 4;
          int cg = col0 + wc * 64 + nh * 32 + nf * 16 + li;
          int t = cg >> 10, h = (cg >> 6) & 15, dk = cg & 63;
#pragma unroll
          for (int ii = 0; ii < 4; ii++) {
            float v = acc[mh][nh][mf][nf][ii];
            int row = rg + ii;
            int b2 = row >> 11, nn = row & 2047;
            size_t idx = ((size_t)((b2 << 4) + h) * 2048 + nn) * 64 + dk;
            if (t == 0)      Qo[idx] = (bf16_t)(v * 0.18033688011112042f);
            else if (t == 1) Ko[idx] = (bf16_t)v;
            else             Vo[idx] = (bf16_t)v;
          }
        }
}

// ---------------- GEMM: A[M][K] bf16 @ BT[N][K] bf16, M-tile templated ----------------
// EPI 1: f32 out + bias (used for the output projection).
template<int EPI, int MT>
__global__ __launch_bounds__(256, 2) void k_gemm(
    const bf16_t* __restrict__ A, const bf16_t* __restrict__ BT, int Klen,
    bf16_t* __restrict__ Qo, bf16_t* __restrict__ Ko, bf16_t* __restrict__ Vo,
    const float* __restrict__ bias, float* __restrict__ Out, int Nout) {
  constexpr int WM = MT / 2;
  constexpr int MF = WM / 16;
  __shared__ bf16_t As[2][MT * 32];
  __shared__ bf16_t Bs[2][4096];
  int tid = threadIdx.x, lane = tid & 63, wid = tid >> 6;
  int row0 = blockIdx.x * MT, col0 = blockIdx.y * 128;
  int wr = wid >> 1, wc = wid & 1;
  int g = lane >> 4, li = lane & 15;

  f32x4 acc[MF][4] = {};

  auto stage = [&](int buf, int kt) {
    int k0 = kt * 32;
#pragma unroll
    for (int j = 0; j < MT / 64; j++) {
      int q = tid + 256 * j;
      int r = q >> 2, part = q & 3;
      gload_lds16(A + (size_t)(row0 + r) * Klen + k0 + part * 8,
                  &As[buf][q * 8]);
    }
#pragma unroll
    for (int j = 0; j < 2; j++) {
      int q = tid + 256 * j;
      int r = q >> 2, part = q & 3;
      gload_lds16(BT + (size_t)(col0 + r) * Klen + k0 + part * 8,
                  &Bs[buf][q * 8]);
    }
  };

  int nk = Klen >> 5;
  stage(0, 0);
  for (int kt = 0; kt < nk; kt++) {
    __syncthreads();
    if (kt + 1 < nk) stage((kt + 1) & 1, kt + 1);
    int buf = kt & 1;
    int kl = g * 8;
    bf16x8 a[MF], b[4];
#pragma unroll
    for (int m = 0; m < MF; m++)
      a[m] = *reinterpret_cast<const bf16x8*>(&As[buf][(wr * WM + m * 16 + li) * 32 + kl]);
#pragma unroll
    for (int n = 0; n < 4; n++)
      b[n] = *reinterpret_cast<const bf16x8*>(&Bs[buf][(wc * 64 + n * 16 + li) * 32 + kl]);
#pragma unroll
    for (int m = 0; m < MF; m++)
#pragma unroll
      for (int n = 0; n < 4; n++)
        acc[m][n] = MFMA16(a[m], b[n], acc[m][n]);
  }

#pragma unroll
  for (int m = 0; m < MF; m++) {
    int rg = row0 + wr * WM + m * 16 + g * 4;
#pragma unroll
    for (int n = 0; n < 4; n++) {
      int cg = col0 + wc * 64 + n * 16 + li;
#pragma unroll
      for (int i = 0; i < 4; i++) {
        float v = acc[m][n][i];
        int row = rg + i;
        if constexpr (EPI == 0) {
          int t = cg >> 10, h = (cg >> 6) & 15, dk = cg & 63;
          int b2 = row >> 11, nn = row & 2047;
          size_t idx = ((size_t)((b2 << 4) + h) * 2048 + nn) * 64 + dk;
          if (t == 0)      Qo[idx] = (bf16_t)(v * 0.18033688011112042f);
          else if (t == 1) Ko[idx] = (bf16_t)v;
          else             Vo[idx] = (bf16_t)v;
        } else {
          Out[(size_t)row * Nout + cg] = v + bias[cg];
        }
      }
    }
  }
}

// ---------------- flash attention v6 ----------------
// 32 q-rows per wave (two 16-row groups), swapped QK^T with lane-local P,
// acc-biased softmax, ones-MFMA row sums, XCD swizzle.
__global__ __launch_bounds__(256, 2) void k_flash(
    const bf16_t* __restrict__ Q, const bf16_t* __restrict__ K,
    const bf16_t* __restrict__ VT, bf16_t* __restrict__ O) {
  __shared__ bf16_t Ks[2][64 * 64];
  __shared__ bf16_t Vs[2][64 * 64];

  int bi = (blockIdx.x & 7) * 64 + (blockIdx.x >> 3);
  int head = bi >> 4, qt = bi & 15;
  int tid = threadIdx.x, lane = tid & 63, wid = tid >> 6;
  int g = lane >> 4, li = lane & 15;

  const bf16_t* Qh = Q + (size_t)head * 131072 + (size_t)qt * 128 * 64;
  const bf16_t* Kh = K + (size_t)head * 131072;
  const bf16_t* Vh = VT + (size_t)head * 131072;

  bf16x8 qf[2][2];
#pragma unroll
  for (int rg = 0; rg < 2; rg++) {
    const bf16_t* qrow = Qh + (size_t)(wid * 32 + rg * 16 + li) * 64;
    qf[rg][0] = *reinterpret_cast<const bf16x8*>(qrow + g * 8);
    qf[rg][1] = *reinterpret_cast<const bf16x8*>(qrow + 32 + g * 8);
  }

  u32x4 onesw;
  onesw[0] = 0x3F803F80u; onesw[1] = 0x3F803F80u;
  onesw[2] = 0x3F803F80u; onesw[3] = 0x3F803F80u;
  bf16x8 ones = __builtin_bit_cast(bf16x8, onesw);

  f32x4 o[2][4] = {};
  f32x4 osum[2] = {};
  float mrun[2] = {0.f, 0.f};

  auto stage = [&](int buf, int t) {
    int kv0 = t * 64;
#pragma unroll
    for (int j = 0; j < 2; j++) {
      int q = tid + 256 * j;
      int key = q >> 3, part = q & 7;
      int sw = (key & 7) ^ (((key >> 3) & 3) << 1);
      gload_lds16(Kh + (size_t)(kv0 + key) * 64 + ((part ^ sw) * 8),
                  &Ks[buf][(tid + j * 256) * 8]);
    }
#pragma unroll
    for (int j = 0; j < 2; j++) {
      int q = tid + 256 * j;
      int dv = q >> 3, part = q & 7;
      gload_lds16(Vh + (size_t)dv * 2048 + kv0 + ((part ^ (dv & 7)) * 8),
                  &Vs[buf][(tid + j * 256) * 8]);
    }
  };

  stage(0, 0);
  for (int t = 0; t < 32; t++) {
    __syncthreads();
    if (t + 1 < 32) stage((t + 1) & 1, t + 1);
    int buf = t & 1;
    char* KsB = (char*)&Ks[buf][0];
    char* VsB = (char*)&Vs[buf][0];

    bf16x8 ka[2][4];
#pragma unroll
    for (int kd = 0; kd < 2; kd++)
#pragma unroll
      for (int nf = 0; nf < 4; nf++) {
        int key = ((li >> 2) << 3) | ((nf & 1) << 2) | (li & 3) | ((nf >> 1) << 5);
        int sw = (key & 7) ^ (((key >> 3) & 3) << 1);
        ka[kd][nf] = *reinterpret_cast<const bf16x8*>(
            KsB + key * 128 + (((kd * 4 + g) ^ sw) << 4));
      }

    f32x4 s[2][4];
#pragma unroll
    for (int rg = 0; rg < 2; rg++) {
      float nm = -mrun[rg];
#pragma unroll
      for (int nf = 0; nf < 4; nf++) {
        s[rg][nf][0] = nm; s[rg][nf][1] = nm; s[rg][nf][2] = nm; s[rg][nf][3] = nm;
      }
    }
    __builtin_amdgcn_s_setprio(1);
#pragma unroll
    for (int kd = 0; kd < 2; kd++)
#pragma unroll
      for (int nf = 0; nf < 4; nf++) {
        s[0][nf] = MFMA16(ka[kd][nf], qf[0][kd], s[0][nf]);
        s[1][nf] = MFMA16(ka[kd][nf], qf[1][kd], s[1][nf]);
      }
    __builtin_amdgcn_s_setprio(0);

    float pmax[2];
#pragma unroll
    for (int rg = 0; rg < 2; rg++) {
      float t0 = fmaxf(fmaxf(s[rg][0][0], s[rg][0][1]), s[rg][0][2]);
      float t1 = fmaxf(fmaxf(s[rg][0][3], s[rg][1][0]), s[rg][1][1]);
      float t2 = fmaxf(fmaxf(s[rg][1][2], s[rg][1][3]), s[rg][2][0]);
      float t3 = fmaxf(fmaxf(s[rg][2][1], s[rg][2][2]), s[rg][2][3]);
      float t4 = fmaxf(fmaxf(s[rg][3][0], s[rg][3][1]), s[rg][3][2]);
      pmax[rg] = fmaxf(fmaxf(fmaxf(t0, t1), fmaxf(t2, t3)), fmaxf(t4, s[rg][3][3]));
    }

    bool ok = (pmax[0] <= 8.f) & (pmax[1] <= 8.f);
    if (!__all(ok)) {
#pragma unroll
      for (int rg = 0; rg < 2; rg++) {
        float v = pmax[rg];
        v = fmaxf(v, __shfl_xor(v, 16));
        v = fmaxf(v, __shfl_xor(v, 32));
        float d = fmaxf(v, 0.f);
        float sc = __builtin_amdgcn_exp2f(-d);
        mrun[rg] += d;
#pragma unroll
        for (int nf = 0; nf < 4; nf++)
#pragma unroll
          for (int i = 0; i < 4; i++) s[rg][nf][i] -= d;
        float osc[4];
#pragma unroll
        for (int i = 0; i < 4; i++) osc[i] = __shfl(sc, g * 4 + i);
#pragma unroll
        for (int nf = 0; nf < 4; nf++)
#pragma unroll
          for (int i = 0; i < 4; i++) o[rg][nf][i] *= osc[i];
#pragma unroll
        for (int i = 0; i < 4; i++) osum[rg][i] *= osc[i];
      }
    }

    bf16x8 pa[2][2];
#pragma unroll
    for (int rg = 0; rg < 2; rg++) {
#pragma unroll
      for (int nf = 0; nf < 4; nf++)
#pragma unroll
        for (int i = 0; i < 4; i++)
          s[rg][nf][i] = __builtin_amdgcn_exp2f(s[rg][nf][i]);
      u32x4 w0, w1;
      w0[0] = cvt_pk_bf16(s[rg][0][0], s[rg][0][1]);
      w0[1] = cvt_pk_bf16(s[rg][0][2], s[rg][0][3]);
      w0[2] = cvt_pk_bf16(s[rg][1][0], s[rg][1][1]);
      w0[3] = cvt_pk_bf16(s[rg][1][2], s[rg][1][3]);
      w1[0] = cvt_pk_bf16(s[rg][2][0], s[rg][2][1]);
      w1[1] = cvt_pk_bf16(s[rg][2][2], s[rg][2][3]);
      w1[2] = cvt_pk_bf16(s[rg][3][0], s[rg][3][1]);
      w1[3] = cvt_pk_bf16(s[rg][3][2], s[rg][3][3]);
      pa[rg][0] = __builtin_bit_cast(bf16x8, w0);
      pa[rg][1] = __builtin_bit_cast(bf16x8, w1);
    }

    __builtin_amdgcn_s_setprio(1);
    osum[0] = MFMA16(pa[0][0], ones, osum[0]);
    osum[0] = MFMA16(pa[0][1], ones, osum[0]);
    osum[1] = MFMA16(pa[1][0], ones, osum[1]);
    osum[1] = MFMA16(pa[1][1], ones, osum[1]);
#pragma unroll
    for (int nfv = 0; nfv < 4; nfv++) {
      int dv = nfv * 16 + li;
      bf16x8 b0 = *reinterpret_cast<const bf16x8*>(
          VsB + dv * 128 + ((g * 16) ^ ((dv & 7) << 4)));
      bf16x8 b1 = *reinterpret_cast<const bf16x8*>(
          VsB + dv * 128 + ((64 + g * 16) ^ ((dv & 7) << 4)));
      o[0][nfv] = MFMA16(pa[0][0], b0, o[0][nfv]);
      o[0][nfv] = MFMA16(pa[0][1], b1, o[0][nfv]);
      o[1][nfv] = MFMA16(pa[1][0], b0, o[1][nfv]);
      o[1][nfv] = MFMA16(pa[1][1], b1, o[1][nfv]);
    }
    __builtin_amdgcn_s_setprio(0);
  }

  int b2 = head >> 4, h = head & 15;
#pragma unroll
  for (int rg = 0; rg < 2; rg++) {
#pragma unroll
    for (int i = 0; i < 4; i++) {
      float inv = 1.f / osum[rg][i];
      int n = qt * 128 + wid * 32 + rg * 16 + g * 4 + i;
      size_t base = ((size_t)b2 * 2048 + n) * 1024 + h * 64;
#pragma unroll
      for (int nfv = 0; nfv < 4; nfv++)
        O[base + nfv * 16 + li] = (bf16_t)(o[rg][nfv][i] * inv);
    }
  }
}

extern "C" void kernel_launch(void* const* d_in, const int* in_sizes, int n_in,
                              void* d_out, int out_size, void* d_ws, size_t ws_size,
                              hipStream_t stream) {
  const float* x    = (const float*)d_in[0];
  const float* Wqkv = (const float*)d_in[1];
  const float* Wout = (const float*)d_in[2];
  const float* bout = (const float*)d_in[3];
  float* out = (float*)d_out;

  char* ws = (char*)d_ws;
  bf16_t* xb    = (bf16_t*)(ws);                          // 8 MB  [4096][1024]
  bf16_t* wqkvT = (bf16_t*)(ws + ((size_t)8  << 20));     // 6 MB  [3072][1024]
  bf16_t* woutT = (bf16_t*)(ws + ((size_t)14 << 20));     // 2 MB  [1024][1024]
  bf16_t* qw    = (bf16_t*)(ws + ((size_t)16 << 20));     // 8 MB  [32][2048][64]
  bf16_t* kw    = (bf16_t*)(ws + ((size_t)24 << 20));     // 8 MB
  bf16_t* vw    = (bf16_t*)(ws + ((size_t)32 << 20));     // 8 MB
  bf16_t* vtw   = (bf16_t*)(ws + ((size_t)40 << 20));     // 8 MB  [32][64][2048]
  bf16_t* ow    = (bf16_t*)(ws + ((size_t)48 << 20));     // 8 MB  [4096][1024]

  // allow 128 KB dynamic LDS for the 8-phase GEMM (idempotent, capture-safe)
  static bool attr_set = false;
  if (!attr_set) {
    hipFuncSetAttribute((const void*)k_gemm_qkv,
                        hipFuncAttributeMaxDynamicSharedMemorySize, 131072);
    attr_set = true;
  }

  k_conv_x<<<2048, 256, 0, stream>>>(x, xb);
  k_transpose_w<<<dim3(96, 32), 256, 0, stream>>>(Wqkv, wqkvT, 1024, 3072);
  k_transpose_w<<<dim3(32, 32), 256, 0, stream>>>(Wout, woutT, 1024, 1024);
  k_gemm_qkv<<<192, 512, 131072, stream>>>(xb, wqkvT, 1024, qw, kw, vw);
  k_vtrans<<<1024, 256, 0, stream>>>(vw, vtw);
  k_flash<<<512, 256, 0, stream>>>(qw, kw, vtw, ow);
  k_gemm<1,64><<<dim3(64, 8), 256, 0, stream>>>(ow, woutT, 1024,
                                                nullptr, nullptr, nullptr,
                                                bout, out, 1024);
}